// Round 20
// baseline (380.842 us; speedup 1.0000x reference)
//
#include <hip/hip_runtime.h>
#include <hip/hip_fp16.h>
#include <math.h>

#define PI_F 3.14159265358979323846f

enum { LOP_NONE=0, LOP_R2C, LOP_PAD };
enum { SOP_REAL=0, SOP_HL };

// ---------------------------------------------------------------------------
// helpers
// ---------------------------------------------------------------------------
__host__ __device__ constexpr int P4(int a, int b){ return a*4 - a*(a-1)/2 + (b-a); }
__host__ __device__ constexpr int P5(int a, int b){ return a*5 - a*(a-1)/2 + (b-a); }

__device__ __forceinline__ unsigned encf(float f){
  unsigned u = __float_as_uint(f);
  return (u & 0x80000000u) ? ~u : (u | 0x80000000u);
}
__device__ __forceinline__ float decf(unsigned u){
  unsigned b = (u & 0x80000000u) ? (u ^ 0x80000000u) : ~u;
  return __uint_as_float(b);
}
__device__ __forceinline__ float2 cxmul(float2 a, float c, float s){
  return make_float2(c*a.x - s*a.y, c*a.y + s*a.x);
}
__device__ __forceinline__ float2 f2add(float2 a, float2 b){ return make_float2(a.x+b.x, a.y+b.y); }
__device__ __forceinline__ float2 f2sub(float2 a, float2 b){ return make_float2(a.x-b.x, a.y-b.y); }
__device__ __forceinline__ float2 h2f(__half2 h){ return __half22float2(h); }
__device__ __forceinline__ __half2 f2h(float2 f){ return __float22half2_rn(f); }

// wave shuffle-reduce -> LDS -> ONE atomicAdd per counter per block.
template<int CNT, int WAVES>
__device__ __forceinline__ void block_reduce_add(float (&acc)[CNT], double* out){
  __shared__ float red[WAVES*CNT];
  int lane = threadIdx.x & 63;
  int wid  = threadIdx.x >> 6;
  #pragma unroll
  for (int k = 0; k < CNT; k++){
    float v = acc[k];
    #pragma unroll
    for (int o = 32; o > 0; o >>= 1) v += __shfl_down(v, o, 64);
    if (lane == 0) red[wid*CNT + k] = v;
  }
  __syncthreads();
  int t = threadIdx.x;
  if (t < CNT){
    double s = 0.0;
    #pragma unroll
    for (int w = 0; w < WAVES; w++) s += (double)red[w*CNT + t];
    atomicAdd(&out[t], s);
  }
  __syncthreads();
}

// scratch variant: reuses caller-provided LDS (cols kernels at 64KB limit).
template<int CNT, int WAVES>
__device__ __forceinline__ void block_reduce_add_sc(float (&acc)[CNT], double* out, float* red){
  __syncthreads();
  int lane = threadIdx.x & 63;
  int wid  = threadIdx.x >> 6;
  #pragma unroll
  for (int k = 0; k < CNT; k++){
    float v = acc[k];
    #pragma unroll
    for (int o = 32; o > 0; o >>= 1) v += __shfl_down(v, o, 64);
    if (lane == 0) red[wid*CNT + k] = v;
  }
  __syncthreads();
  int t = threadIdx.x;
  if (t < CNT){
    double s = 0.0;
    #pragma unroll
    for (int w = 0; w < WAVES; w++) s += (double)red[w*CNT + t];
    atomicAdd(&out[t], s);
  }
}

// float polar grid (ref computes masks in f64 then casts to f32)
__device__ __forceinline__ void polar_f(int iy, int ix, float& lr, float& ang){
  float yn = (float)(iy - 512) * (1.f/512.f);
  float xn = (float)(ix - 512) * (1.f/512.f);
  ang = atan2f(yn, xn);
  float rad = (iy == 512 && ix == 512) ? (1.f/512.f) : sqrtf(xn*xn + yn*yn);
  lr = log2f(rad);
}
__device__ __forceinline__ float f_hi(float lr, float shift){
  float v = fminf(fmaxf(lr - shift, -1.f), 0.f);
  return cosf((PI_F*0.5f) * v);
}
__device__ __forceinline__ float f_lo(float lr, float shift){
  float h = f_hi(lr, shift);
  float q = fminf(fmaxf(1.f - h*h, 0.f), 1.f);
  return sqrtf(q);
}
__device__ __forceinline__ float band_am(float ang, int b){
  float a0 = ang - (PI_F*0.25f)*(float)b + PI_F;
  float a = fmodf(a0, 2.f*PI_F);
  if (a < 0.f) a += 2.f*PI_F;
  a -= PI_F;
  float mk = 0.f;
  if (fabsf(a) < PI_F*0.5f){ float c = cosf(a); mk = 1.78885438199983f*c*c*c; }
  return mk;
}

// radix-4 butterfly on v[4]; fwd: omega=-i
__device__ __forceinline__ void bfly4(float2* v, bool fwd){
  float2 A = f2add(v[0], v[2]), B = f2sub(v[0], v[2]);
  float2 C = f2add(v[1], v[3]), D = f2sub(v[1], v[3]);
  float2 dj = fwd ? make_float2(D.y, -D.x) : make_float2(-D.y, D.x);
  v[0] = f2add(A, C);
  v[1] = f2add(B, dj);
  v[2] = f2sub(A, C);
  v[3] = f2sub(B, dj);
}

// shared radix-4 (radix-2 first if odd log2) Stockham body over sm[N]
template<int N, int T>
__device__ __forceinline__ void fft_rows_body(float2* sm, int t, float dir){
  const bool fwd = (dir < 0.f);
  int Ns = 1;
  if constexpr ((N & 0xAAAAAAAAu) != 0){
    constexpr int NB2 = N/2;
    constexpr int P2 = (NB2 + T - 1)/T;
    float2 a[P2], b[P2];
    #pragma unroll
    for (int p = 0; p < P2; p++){
      int q = t + p*T;
      if (q < NB2){ a[p] = sm[q]; b[p] = sm[q + N/2]; }
    }
    __syncthreads();
    #pragma unroll
    for (int p = 0; p < P2; p++){
      int q = t + p*T;
      if (q < NB2){
        sm[2*q]   = f2add(a[p], b[p]);
        sm[2*q+1] = f2sub(a[p], b[p]);
      }
    }
    __syncthreads();
    Ns = 2;
  }
  constexpr int NB4 = N/4;
  for (; Ns < N; Ns <<= 2){
    float2 v[4];
    int q = t, k = 0;
    if (q < NB4){
      k = q & (Ns - 1);
      #pragma unroll
      for (int r = 0; r < 4; r++) v[r] = sm[q + r*NB4];
      if (k){
        float ang = dir * (PI_F*0.5f) * (float)k / (float)Ns;
        float s1, c1; __sincosf(ang, &s1, &c1);
        float c2 = c1*c1 - s1*s1, s2 = 2.f*c1*s1;
        float c3 = c1*c2 - s1*s2, s3 = c1*s2 + s1*c2;
        v[1] = cxmul(v[1], c1, s1);
        v[2] = cxmul(v[2], c2, s2);
        v[3] = cxmul(v[3], c3, s3);
      }
      bfly4(v, fwd);
    }
    __syncthreads();
    if (q < NB4){
      int dd = ((q - k) << 2) + k;
      sm[dd]        = v[0];
      sm[dd + Ns]   = v[1];
      sm[dd + 2*Ns] = v[2];
      sm[dd + 3*Ns] = v[3];
    }
    __syncthreads();
  }
}

// cols FFT body over sm[N*CB]
template<int N, int CB, int T>
__device__ __forceinline__ void fft_cols_body(float2* sm, int t, float dir){
  constexpr int LCB = (CB==2)?1:(CB==4)?2:(CB==8)?3:4;
  const bool fwd = (dir < 0.f);
  int Ns = 1;
  if constexpr ((N & 0xAAAAAAAAu) != 0){
    constexpr int NB2 = (N/2)*CB;
    constexpr int P2 = (NB2 + T - 1)/T;
    float2 a[P2], b[P2];
    #pragma unroll
    for (int p = 0; p < P2; p++){
      int q = t + p*T;
      if (q < NB2){
        int c = q & (CB-1), tt = q >> LCB;
        a[p] = sm[tt*CB + c];
        b[p] = sm[(tt + N/2)*CB + c];
      }
    }
    __syncthreads();
    #pragma unroll
    for (int p = 0; p < P2; p++){
      int q = t + p*T;
      if (q < NB2){
        int c = q & (CB-1), tt = q >> LCB;
        sm[(2*tt)*CB + c]   = f2add(a[p], b[p]);
        sm[(2*tt+1)*CB + c] = f2sub(a[p], b[p]);
      }
    }
    __syncthreads();
    Ns = 2;
  }
  constexpr int NB4 = (N/4)*CB;
  constexpr int PB = (NB4 + T - 1)/T;
  for (; Ns < N; Ns <<= 2){
    float2 v[PB][4];
    int kk[PB];
    #pragma unroll
    for (int p = 0; p < PB; p++){
      int q = t + p*T;
      if (q < NB4){
        int c = q & (CB-1), tt = q >> LCB;
        int k = tt & (Ns - 1);
        kk[p] = k;
        #pragma unroll
        for (int r = 0; r < 4; r++) v[p][r] = sm[(tt + r*(N/4))*CB + c];
        if (k){
          float ang = dir * (PI_F*0.5f) * (float)k / (float)Ns;
          float s1, c1; __sincosf(ang, &s1, &c1);
          float c2 = c1*c1 - s1*s1, s2 = 2.f*c1*s1;
          float c3 = c1*c2 - s1*s2, s3 = c1*s2 + s1*c2;
          v[p][1] = cxmul(v[p][1], c1, s1);
          v[p][2] = cxmul(v[p][2], c2, s2);
          v[p][3] = cxmul(v[p][3], c3, s3);
        }
        bfly4(v[p], fwd);
      }
    }
    __syncthreads();
    #pragma unroll
    for (int p = 0; p < PB; p++){
      int q = t + p*T;
      if (q < NB4){
        int c = q & (CB-1), tt = q >> LCB;
        int k = kk[p];
        int dd = ((tt - k) << 2) + k;
        sm[(dd)*CB + c]        = v[p][0];
        sm[(dd + Ns)*CB + c]   = v[p][1];
        sm[(dd + 2*Ns)*CB + c] = v[p][2];
        sm[(dd + 3*Ns)*CB + c] = v[p][3];
      }
    }
    __syncthreads();
  }
}

// ---------------------------------------------------------------------------
// simple FFT rows (single image): R2C / NONE / PAD; srcHalf: NONE/PAD read half2
// ---------------------------------------------------------------------------
template<int N>
__global__ __launch_bounds__((N/4 < 64) ? 64 : N/4)
void ps_fft_rows(float2* __restrict__ dst, const void* __restrict__ vsrc,
                 int srcH1, float dir, int xin, int xout, int lop, int srcHalf)
{
  constexpr int T = (N/4 < 64) ? 64 : N/4;
  __shared__ float2 sm[N];
  const int t = threadIdx.x;
  const int l = blockIdx.x;
  float2* dline = dst + (size_t)l*N;
  if (lop == LOP_PAD){
    const int q = N/4;
    const int sl = l - q;
    if (sl < 0 || sl >= srcH1){
      for (int j = t; j < N; j += T) dline[j] = make_float2(0.f, 0.f);
      return;
    }
    if (srcHalf){
      const __half2* s = (const __half2*)vsrc + (size_t)sl*srcH1;
      for (int j = t; j < N; j += T){
        int p = j ^ xin;
        sm[j] = (p >= q && p < q + srcH1) ? h2f(s[p - q]) : make_float2(0.f, 0.f);
      }
    } else {
      const float2* s = (const float2*)vsrc + (size_t)sl*srcH1;
      for (int j = t; j < N; j += T){
        int p = j ^ xin;
        sm[j] = (p >= q && p < q + srcH1) ? s[p - q] : make_float2(0.f, 0.f);
      }
    }
  } else if (lop == LOP_R2C){
    const float* s = (const float*)vsrc + (size_t)l*N;
    for (int j = t; j < N; j += T) sm[j] = make_float2(s[j ^ xin], 0.f);
  } else {
    if (srcHalf){
      const __half2* s = (const __half2*)vsrc + (size_t)l*N;
      for (int j = t; j < N; j += T) sm[j] = h2f(s[j ^ xin]);
    } else {
      const float2* s = (const float2*)vsrc + (size_t)l*N;
      for (int j = t; j < N; j += T) sm[j] = s[j ^ xin];
    }
  }
  __syncthreads();
  fft_rows_body<N, T>(sm, t, dir);
  for (int j = t; j < N; j += T) dline[j ^ xout] = sm[j];
}

// ---------------------------------------------------------------------------
// merged pyramid rows (inverse): one image per block (proven form).
// upMask: 1 = orientation mask on ups slots (s<3); 0 = plain pad (s3 expand2).
// ---------------------------------------------------------------------------
template<int N>
__global__ __launch_bounds__((N/4 < 64) ? 64 : N/4)
void ps_fft_rows_m(__half2* __restrict__ h4, __half2* __restrict__ bandD,
                   __half2* __restrict__ tiledD,
                   const __half2* __restrict__ lodS, const __half2* __restrict__ lodS1,
                   int nA, int h4First, int n, int srcH1, int upMask,
                   int moffB, float shiftB, int moffC, float shiftC, float scale)
{
  constexpr int T = (N/4 < 64) ? 64 : N/4;
  constexpr int XIN = N/2;
  __shared__ float2 sm[N];
  const int t = threadIdx.x;
  const int l = blockIdx.x & (N-1);
  const int img = blockIdx.x / N;

  if (img < nA){
    if (img == 0 && h4First){
      const __half2* s = h4 + (size_t)l*N;
      for (int j = t; j < N; j += T) sm[j] = h2f(s[j ^ XIN]);
    } else {
      const __half2* s = lodS + (size_t)l*N;
      for (int j = t; j < N; j += T) sm[j] = h2f(s[j ^ XIN]);
    }
  } else if (img < nA + 4){
    const int b = img - nA;
    const __half2* s = lodS + (size_t)l*N;
    for (int j = t; j < N; j += T){
      int x = j ^ XIN;
      float lr, ang; polar_f(moffB + l, moffB + x, lr, ang);
      float mf = f_hi(lr, shiftB) * band_am(ang, b);
      float2 v = h2f(s[x]);
      sm[j] = make_float2(-mf*v.y, mf*v.x);
    }
  } else {
    const int b = img - nA - 4;
    const int q = N/4;
    const int sl = l - q;
    if (sl < 0 || sl >= srcH1){
      __half2 z = f2h(make_float2(0.f, 0.f));
      if (tiledD){
        __half2* dl = tiledD + (size_t)img*n;
        for (int j = t; j < N; j += T)
          dl[(size_t)(j >> 3)*(size_t)(N*8) + ((size_t)l << 3) + (j & 7)] = z;
      } else {
        __half2* dl = h4 + (size_t)(img - 4)*n + (size_t)l*N;
        for (int j = t; j < N; j += T) dl[j] = z;
      }
      return;
    }
    const __half2* s = lodS1 + (size_t)sl*srcH1;
    for (int j = t; j < N; j += T){
      int p = j ^ XIN;
      float2 r = make_float2(0.f, 0.f);
      if (p >= q && p < q + srcH1){
        int x = p - q;
        float2 v = h2f(s[x]);
        if (upMask){
          float lr, ang; polar_f(moffC + sl, moffC + x, lr, ang);
          float mf = f_hi(lr, shiftC) * band_am(ang, b);
          r = make_float2(-mf*v.y, mf*v.x);
        } else {
          r = v;
        }
      }
      sm[j] = r;
    }
  }
  __syncthreads();
  fft_rows_body<N, T>(sm, t, +1.f);
  if (tiledD){
    __half2* dl = tiledD + (size_t)img*n;
    for (int j = t; j < N; j += T){
      float2 v = sm[j];
      dl[(size_t)(j >> 3)*(size_t)(N*8) + ((size_t)l << 3) + (j & 7)] =
        f2h(make_float2(v.x*scale, v.y*scale));
    }
  } else {
    __half2* dline;
    if (img < nA)          dline = h4 + (size_t)img*n + (size_t)l*N;
    else if (img < nA + 4) dline = bandD + (size_t)(img - nA)*n + (size_t)l*N;
    else                   dline = h4 + (size_t)(img - 4)*n + (size_t)l*N;
    for (int j = t; j < N; j += T){
      float2 v = sm[j];
      dline[j] = f2h(make_float2(v.x*scale, v.y*scale));
    }
  }
}

// ---------------------------------------------------------------------------
// simple FFT cols (f32 src, single image): SOP_HL / SOP_REAL(+stats)
// ---------------------------------------------------------------------------
template<int N, int CB>
__global__ __launch_bounds__(512)
void ps_fft_cols(const float2* __restrict__ src,
                 __half2* __restrict__ hdst, __half2* __restrict__ lodH,
                 float dir, int xin, int xout, float scale,
                 int sop, float* __restrict__ rdst, double* __restrict__ mout)
{
  constexpr int T = 512;
  constexpr int LCB = (CB==2)?1:(CB==4)?2:(CB==8)?3:4;
  constexpr int NE = N*CB;
  __shared__ float2 sm[NE];
  const int t = threadIdx.x;
  const int c0 = blockIdx.x * CB;
  const float2* sbase = src + c0;

  for (int e = t; e < NE; e += T){
    int j = e >> LCB, c = e & (CB - 1);
    sm[e] = sbase[(size_t)(j ^ xin)*N + c];
  }
  __syncthreads();
  fft_cols_body<N, CB, T>(sm, t, dir);

  if (sop == SOP_HL){
    for (int e = t; e < NE; e += T){
      int j = e >> LCB, c = e & (CB - 1);
      int row = j ^ xout, col = c0 + c;
      float lr, ang; polar_f(row, col, lr, ang);
      float lo = f_lo(lr, 0.f), hi = f_hi(lr, 0.f);
      float2 v = sm[j*CB + c];
      size_t o = (size_t)row*N + col;
      hdst[o] = f2h(make_float2(v.x*hi, v.y*hi));
      lodH[o] = f2h(make_float2(v.x*lo, v.y*lo));
    }
    return;
  }
  for (int e = t; e < NE; e += T){
    int j = e >> LCB, c = e & (CB - 1);
    rdst[(size_t)(j ^ xout)*N + c0 + c] = sm[j*CB + c].x * scale;
  }
  if (mout){
    float acc[5] = {0.f,0.f,0.f,0.f,0.f};
    for (int e = t; e < NE; e += T){
      float r = sm[e].x * scale, r2 = r*r;
      acc[0] += r; acc[1] += r2; acc[2] += r2*r; acc[3] += r2*r2; acc[4] += fabsf(r);
    }
    block_reduce_add_sc<5, 8>(acc, mout, (float*)sm);
  }
}

// ---------------------------------------------------------------------------
// merged pyramid cols (inverse; group A -> real+stats, others half2 out).
// srcT != null: 8-col-chunk tiled intermediate (full-granule reads).
// lpDst != null: ups slot writes real*4 -> lpDst (s3 expand2 fold).
// ---------------------------------------------------------------------------
template<int N, int CB>
__global__ __launch_bounds__(512)
void ps_fft_cols_m(__half2* __restrict__ h4, __half2* __restrict__ bandD,
                   const __half2* __restrict__ srcT,
                   int nA, int n,
                   float* __restrict__ rdst, int rimg, int rmask,
                   double* __restrict__ mout, int mstride,
                   float* __restrict__ lpDst)
{
  constexpr int T = 512;
  constexpr int LCB = (CB==2)?1:(CB==4)?2:(CB==8)?3:4;
  constexpr int NBK = N / CB;
  constexpr int NE = N*CB;
  constexpr int XIN = N/2;
  __shared__ float2 sm[NE];
  const int t = threadIdx.x;
  const int img = blockIdx.x / NBK;
  const int cg  = blockIdx.x % NBK;
  const int c0 = cg * CB;
  __half2* hbase;
  if (img < nA)          hbase = h4 + (size_t)img*n + c0;
  else if (img < nA + 4) hbase = bandD + (size_t)(img - nA)*n + c0;
  else                   hbase = h4 + (size_t)(img - 4)*n + c0;

  if (srcT){
    const __half2* sb = srcT + (size_t)img*n + (size_t)cg*(size_t)(CB*N);
    for (int e = t; e < NE; e += T){
      int j = e >> LCB, c = e & (CB - 1);
      sm[e] = h2f(sb[((j ^ XIN) << LCB) + c]);
    }
  } else {
    for (int e = t; e < NE; e += T){
      int j = e >> LCB, c = e & (CB - 1);
      sm[e] = h2f(hbase[(size_t)(j ^ XIN)*N + c]);
    }
  }
  __syncthreads();
  fft_cols_body<N, CB, T>(sm, t, +1.f);

  if (img < nA){
    if ((rmask >> img) & 1){
      for (int e = t; e < NE; e += T){
        int j = e >> LCB, c = e & (CB - 1);
        rdst[(size_t)img*(size_t)rimg + (size_t)j*N + c0 + c] = sm[j*CB + c].x;
      }
    }
    float acc[5] = {0.f,0.f,0.f,0.f,0.f};
    for (int e = t; e < NE; e += T){
      float r = sm[e].x, r2 = r*r;
      acc[0] += r; acc[1] += r2; acc[2] += r2*r; acc[3] += r2*r2; acc[4] += fabsf(r);
    }
    block_reduce_add_sc<5, 8>(acc, mout + (size_t)img*mstride, (float*)sm);
  } else if (img < nA + 4){
    for (int e = t; e < NE; e += T){
      int j = e >> LCB, c = e & (CB - 1);
      float2 v = sm[j*CB + c];
      hbase[(size_t)j*N + c] = f2h(v);
    }
  } else {
    if (lpDst){
      for (int e = t; e < NE; e += T){
        int j = e >> LCB, c = e & (CB - 1);
        lpDst[(size_t)j*N + c0 + c] = sm[j*CB + c].x * 4.f;   // expand2 x4
      }
    } else {
      for (int e = t; e < NE; e += T){
        int j = e >> LCB, c = e & (CB - 1);
        float2 v = sm[j*CB + c];
        hbase[(size_t)j*N + c] = f2h(make_float2(v.x*4.f, v.y*4.f));
      }
    }
  }
}

// ---------------------------------------------------------------------------
// spatial circular autocorrelation (proven round-8 1px form; bands half2).
// Round-20 experiment: nb cap 128 -> 256 (1px variant; big tasks drop from
// 8 to 4 serial tile iterations, grid ~2x for residency).
// ---------------------------------------------------------------------------
#define MAX_AC_TASKS 9
struct AcTaskTab {
  const void* src[MAX_AC_TASKS];
  int isMag[MAX_AC_TASKS];
  int H[MAX_AC_TASKS];
  int npi[MAX_AC_TASKS];
  int nb[MAX_AC_TASKS];
  int stOff[MAX_AC_TASKS];
  int stStride[MAX_AC_TASKS];
  int blkStart[MAX_AC_TASKS+1];
  int nTasks;
};

__global__ __launch_bounds__(256, 1)
void ps_spat_ac_multi(AcTaskTab tt, double* __restrict__ ST)
{
  __shared__ float tile[40*40];
  const int gb = blockIdx.x;
  int tk = 0;
  while (tk + 1 < tt.nTasks && gb >= tt.blkStart[tk+1]) tk++;
  const int lb  = gb - tt.blkStart[tk];
  const int nb  = tt.nb[tk];
  const int img = lb / nb;
  const int b0  = lb - img*nb;
  const int H = tt.H[tk];
  const int n_per_img = tt.npi[tk];
  const int isMag = tt.isMag[tk];
  const void* vsrc = tt.src[tk];
  const int t = threadIdx.x;
  const int tilesX = H >> 5;
  const int tiles = tilesX * tilesX;
  float acc[41];
  #pragma unroll
  for (int k = 0; k < 41; k++) acc[k] = 0.f;

  for (int tl = b0; tl < tiles; tl += nb){
    int by = tl / tilesX, bx = tl - by*tilesX;
    int y0 = by << 5, x0 = bx << 5;
    __syncthreads();
    for (int e = t; e < 40*40; e += 256){
      int ly = e / 40, lx = e - ly*40;
      int gy = (y0 + ly - 4) & (H - 1);
      int gx = (x0 + lx - 4) & (H - 1);
      float v;
      if (isMag){
        float2 c = h2f(((const __half2*)vsrc)[(size_t)img*n_per_img + (size_t)gy*H + gx]);
        v = sqrtf(c.x*c.x + c.y*c.y);
      } else {
        v = ((const float*)vsrc)[(size_t)img*n_per_img + (size_t)gy*H + gx];
      }
      tile[e] = v;
    }
    __syncthreads();
    for (int p = t; p < 32*32; p += 256){
      int py = p >> 5, px = p & 31;
      const float* row0 = tile + (py+4)*40 + (px+4);
      float c = row0[0];
      #pragma unroll
      for (int dx = 0; dx <= 4; dx++)
        acc[dx] += c * row0[dx];
      #pragma unroll
      for (int dy = 1; dy <= 4; dy++){
        const float* rw = row0 + dy*40;
        #pragma unroll
        for (int dx = -4; dx <= 4; dx++)
          acc[5 + (dy-1)*9 + (dx+4)] += c * rw[dx];
      }
    }
  }
  block_reduce_add<41, 4>(acc, ST + tt.stOff[tk] + (size_t)img*tt.stStride[tk]);
}

// ---------------------------------------------------------------------------
// crop chain: ALL levels 1..4 from lod[0] in ONE launch.
// ---------------------------------------------------------------------------
__global__ __launch_bounds__(256)
void ps_crop_all(__half2* __restrict__ l1, __half2* __restrict__ l2,
                 __half2* __restrict__ l3, __half2* __restrict__ l4,
                 const __half2* __restrict__ l0)
{
  int i = blockIdx.x*blockDim.x + threadIdx.x;
  int k, H;
  if (i < 262144){ k = 1; H = 512; }
  else if (i < 262144 + 65536){ k = 2; H = 256; i -= 262144; }
  else if (i < 262144 + 65536 + 16384){ k = 3; H = 128; i -= 262144 + 65536; }
  else if (i < 262144 + 65536 + 16384 + 4096){ k = 4; H = 64; i -= 262144 + 65536 + 16384; }
  else return;
  int y = i / H, x = i - y*H;
  const int offk = (k==1) ? 256 : (k==2) ? 384 : (k==3) ? 448 : 480;
  int oy = offk + y, ox = offk + x;
  float lr, ang; polar_f(oy, ox, lr, ang);
  float mk = f_lo(lr, -1.f);
  if (k >= 2) mk *= f_lo(lr, -2.f);
  if (k >= 3) mk *= f_lo(lr, -3.f);
  if (k >= 4) mk *= f_lo(lr, -4.f);
  float2 v = h2f(l0[(size_t)oy*1024 + ox]);
  __half2 r = f2h(make_float2(v.x*mk, v.y*mk));
  if (k == 1)      l1[(size_t)y*512 + x] = r;
  else if (k == 2) l2[(size_t)y*256 + x] = r;
  else if (k == 3) l3[(size_t)y*128 + x] = r;
  else             l4[(size_t)y*64  + x] = r;
}

// ---------------------------------------------------------------------------
// reductions
// ---------------------------------------------------------------------------
__global__ void ps_init_mm(unsigned* mm){ mm[0] = 0xFFFFFFFFu; mm[1] = 0u; }

__global__ __launch_bounds__(256, 1)
void ps_im_stats(const float4* __restrict__ x4, int n4, double* out, unsigned* mm){
  float acc[4] = {0.f,0.f,0.f,0.f};
  float mn = INFINITY, mx = -INFINITY;
  for (int i = blockIdx.x*blockDim.x + threadIdx.x; i < n4; i += gridDim.x*blockDim.x){
    float4 v = x4[i];
    float a0 = v.x, a1 = v.y, a2 = v.z, a3 = v.w;
    acc[0] += a0 + a1 + a2 + a3;
    acc[1] += a0*a0 + a1*a1 + a2*a2 + a3*a3;
    acc[2] += a0*a0*a0 + a1*a1*a1 + a2*a2*a2 + a3*a3*a3;
    acc[3] += a0*a0*a0*a0 + a1*a1*a1*a1 + a2*a2*a2*a2 + a3*a3*a3*a3;
    mn = fminf(mn, fminf(fminf(a0,a1), fminf(a2,a3)));
    mx = fmaxf(mx, fmaxf(fmaxf(a0,a1), fmaxf(a2,a3)));
  }
  block_reduce_add<4, 4>(acc, out);
  #pragma unroll
  for (int o = 32; o > 0; o >>= 1){
    mn = fminf(mn, __shfl_down(mn, o, 64));
    mx = fmaxf(mx, __shfl_down(mx, o, 64));
  }
  if ((threadIdx.x & 63) == 0){
    atomicMin(&mm[0], encf(mn));
    atomicMax(&mm[1], encf(mx));
  }
}

struct ScaleATab { const __half2* b[4]; int n[4]; };
__global__ __launch_bounds__(256, 1)
void ps_scaleA_multi(ScaleATab tt, double* __restrict__ ST){
  int s = blockIdx.y;
  int n = tt.n[s];
  if ((size_t)blockIdx.x*blockDim.x >= (size_t)n) return;
  const __half2* bb = tt.b[s];
  double* outp = ST + 64 + s*32;
  float acc[28];
  #pragma unroll
  for (int k = 0; k < 28; k++) acc[k] = 0.f;
  for (int i = blockIdx.x*blockDim.x + threadIdx.x; i < n; i += gridDim.x*blockDim.x){
    float2 v0 = h2f(bb[i]), v1 = h2f(bb[(size_t)n + i]),
           v2 = h2f(bb[2*(size_t)n + i]), v3 = h2f(bb[3*(size_t)n + i]);
    float ab[4] = { sqrtf(v0.x*v0.x+v0.y*v0.y), sqrtf(v1.x*v1.x+v1.y*v1.y),
                    sqrtf(v2.x*v2.x+v2.y*v2.y), sqrtf(v3.x*v3.x+v3.y*v3.y) };
    float re[4] = { v0.x, v1.x, v2.x, v3.x };
    #pragma unroll
    for (int a = 0; a < 4; a++){
      #pragma unroll
      for (int c = a; c < 4; c++){
        acc[P4(a,c)]      += ab[a]*ab[c];
        acc[10 + P4(a,c)] += re[a]*re[c];
      }
      acc[20 + a] += ab[a];
      acc[24 + a] += re[a];
    }
  }
  block_reduce_add<28, 4>(acc, outp);
}
__global__ __launch_bounds__(256, 1)
void ps_scaleB(const __half2* __restrict__ u0, const __half2* __restrict__ u1,
               const __half2* __restrict__ u2, const __half2* __restrict__ u3,
               const __half2* __restrict__ s0, const __half2* __restrict__ s1,
               const __half2* __restrict__ s2, const __half2* __restrict__ s3,
               int n, double* out){
  float acc[72];
  #pragma unroll
  for (int k = 0; k < 72; k++) acc[k] = 0.f;
  for (int i = blockIdx.x*blockDim.x + threadIdx.x; i < n; i += gridDim.x*blockDim.x){
    float2 u[4] = { h2f(u0[i]), h2f(u1[i]), h2f(u2[i]), h2f(u3[i]) };
    float2 bb[4] = { h2f(s0[i]), h2f(s1[i]), h2f(s2[i]), h2f(s3[i]) };
    float au[4], dre[4], dim[4], M[4], R[4];
    #pragma unroll
    for (int c = 0; c < 4; c++){
      float xx = u[c].x, yy = u[c].y;
      float mag = sqrtf(xx*xx + yy*yy);
      float den = mag + 1e-12f;
      au[c] = mag;
      dre[c] = (xx*xx - yy*yy)/den;
      dim[c] = (2.f*xx*yy)/den;
      M[c] = sqrtf(bb[c].x*bb[c].x + bb[c].y*bb[c].y);
      R[c] = bb[c].x;
    }
    #pragma unroll
    for (int c = 0; c < 4; c++){
      acc[c]      += au[c];
      acc[4 + c]  += au[c]*au[c];
      acc[24 + c] += dre[c];
      acc[28 + c] += dim[c];
      acc[32 + c] += dre[c]*dre[c];
      acc[36 + c] += dim[c]*dim[c];
    }
    #pragma unroll
    for (int a = 0; a < 4; a++)
      #pragma unroll
      for (int c = 0; c < 4; c++){
        acc[8 + a*4 + c]  += M[a]*au[c];
        acc[40 + a*4 + c] += R[a]*dre[c];
        acc[56 + a*4 + c] += R[a]*dim[c];
      }
  }
  block_reduce_add<72, 4>(acc, out);
}
__global__ __launch_bounds__(256, 1)
void ps_scaleC(const __half2* __restrict__ s0, const __half2* __restrict__ s1,
               const __half2* __restrict__ s2, const __half2* __restrict__ s3,
               const float* __restrict__ lp, int n, double* out){
  float acc[36];
  #pragma unroll
  for (int k = 0; k < 36; k++) acc[k] = 0.f;
  for (int i = blockIdx.x*blockDim.x + threadIdx.x; i < n; i += gridDim.x*blockDim.x){
    int y = i >> 7, x = i & 127;
    float L[5];
    L[0] = lp[i];
    L[1] = lp[(y << 7) | ((x + 126) & 127)];
    L[2] = lp[(y << 7) | ((x + 2) & 127)];
    L[3] = lp[(((y + 126) & 127) << 7) | x];
    L[4] = lp[(((y + 2) & 127) << 7) | x];
    float R[4] = { h2f(s0[i]).x, h2f(s1[i]).x, h2f(s2[i]).x, h2f(s3[i]).x };
    acc[0] += L[0];
    #pragma unroll
    for (int a = 0; a < 5; a++)
      #pragma unroll
      for (int c = a; c < 5; c++)
        acc[1 + P5(a,c)] += L[a]*L[c];
    #pragma unroll
    for (int a = 0; a < 4; a++)
      #pragma unroll
      for (int j = 0; j < 5; j++)
        acc[16 + a*5 + j] += R[a]*L[j];
  }
  block_reduce_add<36, 4>(acc, out);
}

// ---------------------------------------------------------------------------
// finalize — one thread per output element (layout unchanged)
// ---------------------------------------------------------------------------
__device__ __forceinline__ double d_ns(int s){ double h = (double)(1024 >> s); return h*h; }
__device__ __forceinline__ void d_moments(const double* Mo, double n,
                                          double& sk, double& ku, double& var){
  double m = Mo[0]/n, e2 = Mo[1]/n, e3 = Mo[2]/n, e4 = Mo[3]/n;
  var = e2 - m*m;
  double c3 = e3 - 3.0*m*e2 + 2.0*m*m*m;
  double c4 = e4 - 4.0*m*e3 + 6.0*m*m*e2 - 3.0*m*m*m*m;
  sk = c3/pow(var,1.5); ku = c4/(var*var);
}
__device__ __forceinline__ int ac_o(int w){
  int dy = w/9 - 4, dx = w - (w/9)*9 - 4;
  int ady = dy, adx = dx;
  if (dy < 0 || (dy == 0 && dx < 0)){ ady = -dy; adx = -dx; }
  return (ady == 0) ? adx : (5 + (ady-1)*9 + (adx+4));
}

__global__ __launch_bounds__(256)
void ps_finalize(const double* __restrict__ ST, const unsigned* __restrict__ MM,
                 float* __restrict__ out, int out_size){
  int idx = blockIdx.x*blockDim.x + threadIdx.x;
  if (idx >= out_size) return;
  const double n0 = 1048576.0;
  double val = 0.0;

  if (idx <= 5){
    if (idx == 4){ out[4] = decf(MM[0]); return; }
    if (idx == 5){ out[5] = decf(MM[1]); return; }
    double sk, ku, v; d_moments(ST, n0, sk, ku, v);
    val = (idx == 0) ? ST[0]/n0 : (idx == 1) ? v : (idx == 2) ? sk : ku;
  } else if (idx == 6){
    val = ST[8]/n0;
  } else if (idx <= 22){
    int i = idx - 7; int s = i >> 2, b = i & 3;
    val = ST[64 + s*32 + 20 + b] / d_ns(s);
  } else if (idx == 23){
    val = ST[10 + 4*6 + 4] / 4096.0;
  } else if (idx <= 1319){                      // band-mag ACs
    int i = idx - 24; int w = i >> 4; int j = i & 15;
    int s = j >> 2, b = j & 3;
    double n = d_ns(s);
    const double* R = ST + 752 + j*48;
    double mu = ST[64 + s*32 + 20 + b]/n, mu2 = mu*mu;
    int o = ac_o(w);
    val = (R[o]/n - mu2) / (R[0]/n - mu2 + 1e-12);
  } else if (idx <= 1329){                      // skew_r / kurt_r
    int i = idx - 1320; bool kq = (i >= 5); int r = kq ? i - 5 : i;
    double n = (r == 4) ? 4096.0 : d_ns(r);
    double sk, ku, v; d_moments(ST + 10 + r*6, n, sk, ku, v);
    val = kq ? ku : sk;
  } else if (idx <= 1734){                      // recon ACs
    int i = idx - 1330; int w = i / 5; int r = i - w*5;
    double n = (r == 4) ? 4096.0 : d_ns(r);
    const double* R = ST + 512 + r*48;
    double mu = ST[10 + r*6]/n, mu2 = mu*mu;
    int o = ac_o(w);
    val = (R[o]/n - mu2) / (R[0]/n - mu2 + 1e-12);
  } else if (idx <= 1739){                      // std_r
    int r = idx - 1735;
    double n = (r == 4) ? 4096.0 : d_ns(r);
    double sk, ku, v; d_moments(ST + 10 + r*6, n, sk, ku, v);
    val = sqrt(v);
  } else if (idx <= 1819){                      // com
    int i = idx - 1740; int s = i % 5; int q = i / 5; int a = q >> 2, b = q & 3;
    if (s < 4){
      double n = d_ns(s); const double* A = ST + 64 + s*32;
      double ma = A[20+a]/n, mb = A[20+b]/n;
      double caa = A[P4(a,a)]/n - ma*ma, cbb = A[P4(b,b)]/n - mb*mb;
      int lo = a < b ? a : b, hi = a < b ? b : a;
      double cab = A[P4(lo,hi)]/n - ma*mb;
      val = cab / (sqrt(caa)*sqrt(cbb) + 1e-12);
    }
  } else if (idx <= 1883){                      // csm
    int i = idx - 1820; int s = i & 3; int q = i >> 2; int a = q >> 2, c = q & 3;
    if (s < 3){
      double n = d_ns(s); const double* A = ST + 64 + s*32; const double* B = ST + 192 + s*80;
      double mM = A[20+a]/n; double sdM = sqrt(A[P4(a,a)]/n - mM*mM);
      double mU = B[c]/n;    double sdU = sqrt(B[4+c]/n - mU*mU);
      val = (B[8 + a*4 + c]/n - mM*mU) / (sdM*sdU + 1e-12);
    }
  } else if (idx <= 2203){                      // cor
    int i = idx - 1884; int s = i % 5; int q = i / 5; int a = q >> 3, b = q & 7;
    if (s < 4){
      if (a < 4 && b < 4){
        double n = d_ns(s); const double* A = ST + 64 + s*32;
        double ma = A[24+a]/n, mb = A[24+b]/n;
        double caa = A[10+P4(a,a)]/n - ma*ma, cbb = A[10+P4(b,b)]/n - mb*mb;
        int lo = a < b ? a : b, hi = a < b ? b : a;
        double cab = A[10+P4(lo,hi)]/n - ma*mb;
        val = cab / (sqrt(caa)*sqrt(cbb) + 1e-12);
      }
    } else {
      if (a < 5 && b < 5){
        const double* C = ST + 432; const double n3 = 16384.0;
        double lb = C[0]/n3;
        double caa = C[1+P5(a,a)]/n3 - lb*lb, cbb = C[1+P5(b,b)]/n3 - lb*lb;
        int lo = a < b ? a : b, hi = a < b ? b : a;
        double cab = C[1+P5(lo,hi)]/n3 - lb*lb;
        val = cab / (sqrt(caa)*sqrt(cbb) + 1e-12);
      }
    }
  } else if (idx <= 2459){                      // csr
    int i = idx - 2204; int s = i & 3; int q = i >> 2; int a = q >> 3, c = q & 7;
    if (a < 4){
      double n = d_ns(s); const double* A = ST + 64 + s*32;
      double mR = A[24+a]/n; double sdR = sqrt(A[10+P4(a,a)]/n - mR*mR);
      if (s < 3 && c < 8){
        const double* B = ST + 192 + s*80;
        if (c < 4){
          double md = B[24+c]/n; double sd = sqrt(B[32+c]/n - md*md);
          val = (B[40 + a*4 + c]/n - mR*md) / (sdR*sd + 1e-12);
        } else {
          int cc = c - 4;
          double md = B[28+cc]/n; double sd = sqrt(B[36+cc]/n - md*md);
          val = (B[56 + a*4 + cc]/n - mR*md) / (sdR*sd + 1e-12);
        }
      } else if (s == 3 && c < 5){
        const double* C = ST + 432; const double n3 = 16384.0;
        double lb = C[0]/n3;
        double sdL = sqrt(C[1+P5(c,c)]/n3 - lb*lb);
        val = (C[16 + a*5 + c]/n3 - mR*lb) / (sdR*sdL + 1e-12);
      }
    }
  } else {
    val = ST[5]/n0 - (ST[4]/n0)*(ST[4]/n0);
  }
  out[idx] = (float)val;
}

// ---------------------------------------------------------------------------
// host orchestration
// ---------------------------------------------------------------------------
static void rows_s(int H, float2* dst, const void* src, int srcH1,
                   float dir, int xin, int xout, int lop, int srcHalf, hipStream_t st){
  dim3 g(H);
  switch (H){
    case 64:   ps_fft_rows<64>  <<<g, 64,  0, st>>>(dst, src, srcH1, dir, xin, xout, lop, srcHalf); break;
    case 128:  ps_fft_rows<128> <<<g, 64,  0, st>>>(dst, src, srcH1, dir, xin, xout, lop, srcHalf); break;
    case 256:  ps_fft_rows<256> <<<g, 64,  0, st>>>(dst, src, srcH1, dir, xin, xout, lop, srcHalf); break;
    case 512:  ps_fft_rows<512> <<<g, 128, 0, st>>>(dst, src, srcH1, dir, xin, xout, lop, srcHalf); break;
    case 1024: ps_fft_rows<1024><<<g, 256, 0, st>>>(dst, src, srcH1, dir, xin, xout, lop, srcHalf); break;
    default: break;
  }
}
static void cols_s(int H, const float2* src, __half2* hdst, __half2* lodH,
                   float dir, int xin, int xout, float scale,
                   int sop, float* rdst, double* mout, hipStream_t st){
  switch (H){
    case 64:   ps_fft_cols<64,16>  <<<dim3(64/16),  512, 0, st>>>(src, hdst, lodH, dir, xin, xout, scale, sop, rdst, mout); break;
    case 128:  ps_fft_cols<128,16> <<<dim3(128/16), 512, 0, st>>>(src, hdst, lodH, dir, xin, xout, scale, sop, rdst, mout); break;
    case 256:  ps_fft_cols<256,16> <<<dim3(256/16), 512, 0, st>>>(src, hdst, lodH, dir, xin, xout, scale, sop, rdst, mout); break;
    case 512:  ps_fft_cols<512,16> <<<dim3(512/16), 512, 0, st>>>(src, hdst, lodH, dir, xin, xout, scale, sop, rdst, mout); break;
    case 1024: ps_fft_cols<1024,8> <<<dim3(1024/8), 512, 0, st>>>(src, hdst, lodH, dir, xin, xout, scale, sop, rdst, mout); break;
    default: break;
  }
}
static void rows_m(int H, __half2* h4, __half2* bandD, __half2* tiledD,
                   const __half2* lodS, const __half2* lodS1,
                   int nA, int h4First, int nimg, int n, int srcH1, int upMask,
                   int moffB, float shiftB, int moffC, float shiftC, float scale, hipStream_t st){
  dim3 g(nimg * H);
  switch (H){
    case 128:  ps_fft_rows_m<128> <<<g, 64,  0, st>>>(h4, bandD, tiledD, lodS, lodS1, nA, h4First, n, srcH1, upMask, moffB, shiftB, moffC, shiftC, scale); break;
    case 256:  ps_fft_rows_m<256> <<<g, 64,  0, st>>>(h4, bandD, tiledD, lodS, lodS1, nA, h4First, n, srcH1, upMask, moffB, shiftB, moffC, shiftC, scale); break;
    case 512:  ps_fft_rows_m<512> <<<g, 128, 0, st>>>(h4, bandD, tiledD, lodS, lodS1, nA, h4First, n, srcH1, upMask, moffB, shiftB, moffC, shiftC, scale); break;
    case 1024: ps_fft_rows_m<1024><<<g, 256, 0, st>>>(h4, bandD, tiledD, lodS, lodS1, nA, h4First, n, srcH1, upMask, moffB, shiftB, moffC, shiftC, scale); break;
    default: break;
  }
}
static void cols_m(int H, __half2* h4, __half2* bandD, const __half2* srcT,
                   int nA, int nimg, int n,
                   float* rdst, int rimg, int rmask, double* mout, int mstride,
                   float* lpDst, hipStream_t st){
  switch (H){
    case 128:  ps_fft_cols_m<128,16> <<<dim3(nimg*(128/16)), 512, 0, st>>>(h4, bandD, srcT, nA, n, rdst, rimg, rmask, mout, mstride, lpDst); break;
    case 256:  ps_fft_cols_m<256,16> <<<dim3(nimg*(256/16)), 512, 0, st>>>(h4, bandD, srcT, nA, n, rdst, rimg, rmask, mout, mstride, lpDst); break;
    case 512:  ps_fft_cols_m<512,16> <<<dim3(nimg*(512/16)), 512, 0, st>>>(h4, bandD, srcT, nA, n, rdst, rimg, rmask, mout, mstride, lpDst); break;
    case 1024: ps_fft_cols_m<1024,8> <<<dim3(nimg*(1024/8)), 512, 0, st>>>(h4, bandD, srcT, nA, n, rdst, rimg, rmask, mout, mstride, lpDst); break;
    default: break;
  }
}

static inline dim3 gr(int n){ return dim3((n + 255)/256); }
static inline int  rblocks(int n){ int b = (n + 255)/256; return b > 512 ? 512 : b; }

#define FWD (-1.0f)
#define INV (+1.0f)

extern "C" void kernel_launch(void* const* d_in, const int* in_sizes, int n_in,
                              void* d_out, int out_size, void* d_ws, size_t ws_size,
                              hipStream_t stream){
  (void)in_sizes; (void)n_in;
  const float* im = (const float*)d_in[0];
  float* out = (float*)d_out;

  const int Hs[5]   = {1024, 512, 256, 128, 64};
  const int offs[5] = {0, 256, 384, 448, 480};

  // ---- carve workspace ----
  char* base = (char*)d_ws;
  size_t off = 0;
  auto carve = [&](size_t bytes)->void*{
    void* r = base + off;
    off = (off + bytes + 255) & ~(size_t)255;
    return r;
  };
  const int n0 = 1024*1024;
  __half2* lod[5];
  for (int s = 0; s < 5; s++) lod[s] = (__half2*)carve((size_t)Hs[s]*Hs[s]*sizeof(__half2));
  __half2* band[4];
  for (int s = 0; s < 4; s++) band[s] = (__half2*)carve((size_t)4*Hs[s]*Hs[s]*sizeof(__half2));
  float* reals0 = (float*)carve((size_t)2*n0*sizeof(float));
  float* recon[5];
  recon[0] = reals0 + n0;
  for (int s = 1; s < 5; s++) recon[s] = (float*)carve((size_t)Hs[s]*Hs[s]*sizeof(float));
  float* lp = (float*)carve(128*128*sizeof(float));
  float2* scrF = (float2*)carve((size_t)n0*sizeof(float2));
  __half2* h4 = (__half2*)carve((size_t)6*n0*sizeof(__half2));
  __half2* hInt = (__half2*)carve((size_t)10*n0*sizeof(__half2));  // s0 tiled intermediate
  double* ST = (double*)carve(2048*sizeof(double));
  unsigned* MM = (unsigned*)carve(64*sizeof(unsigned));
  if (off > ws_size) return;

  // ---- init ----
  hipMemsetAsync(ST, 0, 2048*sizeof(double), stream);
  ps_init_mm<<<1, 1, 0, stream>>>(MM);
  ps_im_stats<<<256, 256, 0, stream>>>((const float4*)im, n0/4, ST + 0, MM);

  // ---- imdft (shifted); cols fuses radial masks:
  //      h4[0] = hi*V (half), lod[0] = lo*V (half) ----
  rows_s(1024, scrF, im, 0, FWD, 0, 512, LOP_R2C, 0, stream);
  cols_s(1024, scrF, h4, lod[0], FWD, 0, 512, 1.0f, SOP_HL, nullptr, nullptr, stream);

  // ---- whole crop chain in one launch ----
  ps_crop_all<<<gr(262144 + 65536 + 16384 + 4096), 256, 0, stream>>>(
      lod[1], lod[2], lod[3], lod[4], lod[0]);

  // ---- pyramid scales: merged rows+cols pair per scale
  //      (s3 additionally carries the lowpass expand2 as an unmasked up) ----
  for (int s = 0; s < 4; s++){
    int H = Hs[s], n = H*H;
    float invn = 1.0f/((float)H*(float)H);
    int nA = (s == 0) ? 2 : 1;
    int nups = (s < 3) ? 4 : 1;
    int nimg = nA + 4 + nups;
    int upMask = (s < 3) ? 1 : 0;
    __half2* tD = (s == 0) ? hInt : nullptr;
    rows_m(H, h4, band[s], tD, lod[s], lod[s+1], nA, (s == 0) ? 1 : 0, nimg, n, Hs[s+1],
           upMask, offs[s], -(float)(s+1), offs[s+1], -(float)(s+2), invn, stream);
    float* rT = (s == 0) ? reals0 : recon[s];
    int rimg = (s == 0) ? n0 : 0;
    int rmask = (s == 0) ? 2 : 1;
    double* mT = (s == 0) ? (ST + 4) : (ST + 10 + s*6);
    int mstr = (s == 0) ? 6 : 0;
    float* lpD = (s == 3) ? lp : nullptr;
    cols_m(H, h4, band[s], tD, nA, nimg, n, rT, rimg, rmask, mT, mstr, lpD, stream);
    if (s < 3){
      __half2* u = h4 + (size_t)nA*n;
      ps_scaleB<<<rblocks(n), 256, 0, stream>>>(u, u+n, u+2*(size_t)n, u+3*(size_t)n,
                                                band[s], band[s]+n, band[s]+2*(size_t)n, band[s]+3*(size_t)n,
                                                n, ST + 192 + s*80);
    }
  }
  // lowpass recon (lod[4] half -> f32 fft)
  rows_s(64, scrF, lod[4], 0, INV, 32, 0, LOP_NONE, 1, stream);
  cols_s(64, scrF, nullptr, nullptr, INV, 32, 0, 1.0f/4096.f, SOP_REAL, recon[4], ST + 34, stream);
  ps_scaleC<<<rblocks(16384), 256, 0, stream>>>(band[3], band[3]+16384, band[3]+2*16384, band[3]+3*16384,
                                                lp, 16384, ST + 432);

  // ---- all 21 autocorrelations in one launch (big tasks first, nb<=256) ----
  {
    AcTaskTab tt{};
    int nt = 0, blk = 0;
    auto addTask = [&](const void* src, int isMag, int H, int nimgs, int stOff){
      int tiles = (H>>5)*(H>>5);
      int nb = tiles < 256 ? tiles : 256;
      tt.src[nt] = src; tt.isMag[nt] = isMag; tt.H[nt] = H; tt.npi[nt] = H*H;
      tt.nb[nt] = nb; tt.stOff[nt] = stOff; tt.stStride[nt] = 48;
      tt.blkStart[nt] = blk; blk += nb*nimgs; nt++;
    };
    addTask(band[0], 1, 1024, 4, 752 + 0*4*48);
    addTask(recon[0], 0, 1024, 1, 512 + 0*48);
    addTask(band[1], 1, 512, 4, 752 + 1*4*48);
    addTask(recon[1], 0, 512, 1, 512 + 1*48);
    addTask(band[2], 1, 256, 4, 752 + 2*4*48);
    addTask(recon[2], 0, 256, 1, 512 + 2*48);
    addTask(band[3], 1, 128, 4, 752 + 3*4*48);
    addTask(recon[3], 0, 128, 1, 512 + 3*48);
    addTask(recon[4], 0, 64, 1, 512 + 4*48);
    tt.blkStart[nt] = blk; tt.nTasks = nt;
    ps_spat_ac_multi<<<dim3(blk), 256, 0, stream>>>(tt, ST);
  }

  // ---- per-scale band Grams (one launch) ----
  {
    ScaleATab ta{};
    for (int s = 0; s < 4; s++){ ta.b[s] = band[s]; ta.n[s] = Hs[s]*Hs[s]; }
    ps_scaleA_multi<<<dim3(512, 4), 256, 0, stream>>>(ta, ST);
  }

  // ---- finalize ----
  ps_finalize<<<gr(out_size), 256, 0, stream>>>(ST, MM, out, out_size);
}

// Round 21
// 363.786 us; speedup vs baseline: 1.0469x; 1.0469x over previous
//
#include <hip/hip_runtime.h>
#include <hip/hip_fp16.h>
#include <math.h>

#define PI_F 3.14159265358979323846f

enum { LOP_NONE=0, LOP_R2C, LOP_PAD };
enum { SOP_REAL=0, SOP_HL };

// ---------------------------------------------------------------------------
// helpers
// ---------------------------------------------------------------------------
__host__ __device__ constexpr int P4(int a, int b){ return a*4 - a*(a-1)/2 + (b-a); }
__host__ __device__ constexpr int P5(int a, int b){ return a*5 - a*(a-1)/2 + (b-a); }

__device__ __forceinline__ unsigned encf(float f){
  unsigned u = __float_as_uint(f);
  return (u & 0x80000000u) ? ~u : (u | 0x80000000u);
}
__device__ __forceinline__ float decf(unsigned u){
  unsigned b = (u & 0x80000000u) ? (u ^ 0x80000000u) : ~u;
  return __uint_as_float(b);
}
__device__ __forceinline__ float2 cxmul(float2 a, float c, float s){
  return make_float2(c*a.x - s*a.y, c*a.y + s*a.x);
}
__device__ __forceinline__ float2 f2add(float2 a, float2 b){ return make_float2(a.x+b.x, a.y+b.y); }
__device__ __forceinline__ float2 f2sub(float2 a, float2 b){ return make_float2(a.x-b.x, a.y-b.y); }
__device__ __forceinline__ float2 h2f(__half2 h){ return __half22float2(h); }
__device__ __forceinline__ __half2 f2h(float2 f){ return __float22half2_rn(f); }

// wave shuffle-reduce -> LDS -> ONE atomicAdd per counter per block.
template<int CNT, int WAVES>
__device__ __forceinline__ void block_reduce_add(float (&acc)[CNT], double* out){
  __shared__ float red[WAVES*CNT];
  int lane = threadIdx.x & 63;
  int wid  = threadIdx.x >> 6;
  #pragma unroll
  for (int k = 0; k < CNT; k++){
    float v = acc[k];
    #pragma unroll
    for (int o = 32; o > 0; o >>= 1) v += __shfl_down(v, o, 64);
    if (lane == 0) red[wid*CNT + k] = v;
  }
  __syncthreads();
  int t = threadIdx.x;
  if (t < CNT){
    double s = 0.0;
    #pragma unroll
    for (int w = 0; w < WAVES; w++) s += (double)red[w*CNT + t];
    atomicAdd(&out[t], s);
  }
  __syncthreads();
}

// scratch variant: reuses caller-provided LDS (cols kernels at 64KB limit).
template<int CNT, int WAVES>
__device__ __forceinline__ void block_reduce_add_sc(float (&acc)[CNT], double* out, float* red){
  __syncthreads();
  int lane = threadIdx.x & 63;
  int wid  = threadIdx.x >> 6;
  #pragma unroll
  for (int k = 0; k < CNT; k++){
    float v = acc[k];
    #pragma unroll
    for (int o = 32; o > 0; o >>= 1) v += __shfl_down(v, o, 64);
    if (lane == 0) red[wid*CNT + k] = v;
  }
  __syncthreads();
  int t = threadIdx.x;
  if (t < CNT){
    double s = 0.0;
    #pragma unroll
    for (int w = 0; w < WAVES; w++) s += (double)red[w*CNT + t];
    atomicAdd(&out[t], s);
  }
}

// float polar grid (ref computes masks in f64 then casts to f32)
__device__ __forceinline__ void polar_f(int iy, int ix, float& lr, float& ang){
  float yn = (float)(iy - 512) * (1.f/512.f);
  float xn = (float)(ix - 512) * (1.f/512.f);
  ang = atan2f(yn, xn);
  float rad = (iy == 512 && ix == 512) ? (1.f/512.f) : sqrtf(xn*xn + yn*yn);
  lr = log2f(rad);
}
__device__ __forceinline__ float f_hi(float lr, float shift){
  float v = fminf(fmaxf(lr - shift, -1.f), 0.f);
  return cosf((PI_F*0.5f) * v);
}
__device__ __forceinline__ float f_lo(float lr, float shift){
  float h = f_hi(lr, shift);
  float q = fminf(fmaxf(1.f - h*h, 0.f), 1.f);
  return sqrtf(q);
}
__device__ __forceinline__ float band_am(float ang, int b){
  float a0 = ang - (PI_F*0.25f)*(float)b + PI_F;
  float a = fmodf(a0, 2.f*PI_F);
  if (a < 0.f) a += 2.f*PI_F;
  a -= PI_F;
  float mk = 0.f;
  if (fabsf(a) < PI_F*0.5f){ float c = cosf(a); mk = 1.78885438199983f*c*c*c; }
  return mk;
}

// radix-4 butterfly on v[4]; fwd: omega=-i
__device__ __forceinline__ void bfly4(float2* v, bool fwd){
  float2 A = f2add(v[0], v[2]), B = f2sub(v[0], v[2]);
  float2 C = f2add(v[1], v[3]), D = f2sub(v[1], v[3]);
  float2 dj = fwd ? make_float2(D.y, -D.x) : make_float2(-D.y, D.x);
  v[0] = f2add(A, C);
  v[1] = f2add(B, dj);
  v[2] = f2sub(A, C);
  v[3] = f2sub(B, dj);
}

// shared radix-4 (radix-2 first if odd log2) Stockham body over sm[N]
template<int N, int T>
__device__ __forceinline__ void fft_rows_body(float2* sm, int t, float dir){
  const bool fwd = (dir < 0.f);
  int Ns = 1;
  if constexpr ((N & 0xAAAAAAAAu) != 0){
    constexpr int NB2 = N/2;
    constexpr int P2 = (NB2 + T - 1)/T;
    float2 a[P2], b[P2];
    #pragma unroll
    for (int p = 0; p < P2; p++){
      int q = t + p*T;
      if (q < NB2){ a[p] = sm[q]; b[p] = sm[q + N/2]; }
    }
    __syncthreads();
    #pragma unroll
    for (int p = 0; p < P2; p++){
      int q = t + p*T;
      if (q < NB2){
        sm[2*q]   = f2add(a[p], b[p]);
        sm[2*q+1] = f2sub(a[p], b[p]);
      }
    }
    __syncthreads();
    Ns = 2;
  }
  constexpr int NB4 = N/4;
  for (; Ns < N; Ns <<= 2){
    float2 v[4];
    int q = t, k = 0;
    if (q < NB4){
      k = q & (Ns - 1);
      #pragma unroll
      for (int r = 0; r < 4; r++) v[r] = sm[q + r*NB4];
      if (k){
        float ang = dir * (PI_F*0.5f) * (float)k / (float)Ns;
        float s1, c1; __sincosf(ang, &s1, &c1);
        float c2 = c1*c1 - s1*s1, s2 = 2.f*c1*s1;
        float c3 = c1*c2 - s1*s2, s3 = c1*s2 + s1*c2;
        v[1] = cxmul(v[1], c1, s1);
        v[2] = cxmul(v[2], c2, s2);
        v[3] = cxmul(v[3], c3, s3);
      }
      bfly4(v, fwd);
    }
    __syncthreads();
    if (q < NB4){
      int dd = ((q - k) << 2) + k;
      sm[dd]        = v[0];
      sm[dd + Ns]   = v[1];
      sm[dd + 2*Ns] = v[2];
      sm[dd + 3*Ns] = v[3];
    }
    __syncthreads();
  }
}

// cols FFT body over sm[N*CB]
template<int N, int CB, int T>
__device__ __forceinline__ void fft_cols_body(float2* sm, int t, float dir){
  constexpr int LCB = (CB==2)?1:(CB==4)?2:(CB==8)?3:4;
  const bool fwd = (dir < 0.f);
  int Ns = 1;
  if constexpr ((N & 0xAAAAAAAAu) != 0){
    constexpr int NB2 = (N/2)*CB;
    constexpr int P2 = (NB2 + T - 1)/T;
    float2 a[P2], b[P2];
    #pragma unroll
    for (int p = 0; p < P2; p++){
      int q = t + p*T;
      if (q < NB2){
        int c = q & (CB-1), tt = q >> LCB;
        a[p] = sm[tt*CB + c];
        b[p] = sm[(tt + N/2)*CB + c];
      }
    }
    __syncthreads();
    #pragma unroll
    for (int p = 0; p < P2; p++){
      int q = t + p*T;
      if (q < NB2){
        int c = q & (CB-1), tt = q >> LCB;
        sm[(2*tt)*CB + c]   = f2add(a[p], b[p]);
        sm[(2*tt+1)*CB + c] = f2sub(a[p], b[p]);
      }
    }
    __syncthreads();
    Ns = 2;
  }
  constexpr int NB4 = (N/4)*CB;
  constexpr int PB = (NB4 + T - 1)/T;
  for (; Ns < N; Ns <<= 2){
    float2 v[PB][4];
    int kk[PB];
    #pragma unroll
    for (int p = 0; p < PB; p++){
      int q = t + p*T;
      if (q < NB4){
        int c = q & (CB-1), tt = q >> LCB;
        int k = tt & (Ns - 1);
        kk[p] = k;
        #pragma unroll
        for (int r = 0; r < 4; r++) v[p][r] = sm[(tt + r*(N/4))*CB + c];
        if (k){
          float ang = dir * (PI_F*0.5f) * (float)k / (float)Ns;
          float s1, c1; __sincosf(ang, &s1, &c1);
          float c2 = c1*c1 - s1*s1, s2 = 2.f*c1*s1;
          float c3 = c1*c2 - s1*s2, s3 = c1*s2 + s1*c2;
          v[p][1] = cxmul(v[p][1], c1, s1);
          v[p][2] = cxmul(v[p][2], c2, s2);
          v[p][3] = cxmul(v[p][3], c3, s3);
        }
        bfly4(v[p], fwd);
      }
    }
    __syncthreads();
    #pragma unroll
    for (int p = 0; p < PB; p++){
      int q = t + p*T;
      if (q < NB4){
        int c = q & (CB-1), tt = q >> LCB;
        int k = kk[p];
        int dd = ((tt - k) << 2) + k;
        sm[(dd)*CB + c]        = v[p][0];
        sm[(dd + Ns)*CB + c]   = v[p][1];
        sm[(dd + 2*Ns)*CB + c] = v[p][2];
        sm[(dd + 3*Ns)*CB + c] = v[p][3];
      }
    }
    __syncthreads();
  }
}

// ---------------------------------------------------------------------------
// simple FFT rows (single image): R2C / NONE / PAD; srcHalf: NONE/PAD read half2
// ---------------------------------------------------------------------------
template<int N>
__global__ __launch_bounds__((N/4 < 64) ? 64 : N/4)
void ps_fft_rows(float2* __restrict__ dst, const void* __restrict__ vsrc,
                 int srcH1, float dir, int xin, int xout, int lop, int srcHalf)
{
  constexpr int T = (N/4 < 64) ? 64 : N/4;
  __shared__ float2 sm[N];
  const int t = threadIdx.x;
  const int l = blockIdx.x;
  float2* dline = dst + (size_t)l*N;
  if (lop == LOP_PAD){
    const int q = N/4;
    const int sl = l - q;
    if (sl < 0 || sl >= srcH1){
      for (int j = t; j < N; j += T) dline[j] = make_float2(0.f, 0.f);
      return;
    }
    if (srcHalf){
      const __half2* s = (const __half2*)vsrc + (size_t)sl*srcH1;
      for (int j = t; j < N; j += T){
        int p = j ^ xin;
        sm[j] = (p >= q && p < q + srcH1) ? h2f(s[p - q]) : make_float2(0.f, 0.f);
      }
    } else {
      const float2* s = (const float2*)vsrc + (size_t)sl*srcH1;
      for (int j = t; j < N; j += T){
        int p = j ^ xin;
        sm[j] = (p >= q && p < q + srcH1) ? s[p - q] : make_float2(0.f, 0.f);
      }
    }
  } else if (lop == LOP_R2C){
    const float* s = (const float*)vsrc + (size_t)l*N;
    for (int j = t; j < N; j += T) sm[j] = make_float2(s[j ^ xin], 0.f);
  } else {
    if (srcHalf){
      const __half2* s = (const __half2*)vsrc + (size_t)l*N;
      for (int j = t; j < N; j += T) sm[j] = h2f(s[j ^ xin]);
    } else {
      const float2* s = (const float2*)vsrc + (size_t)l*N;
      for (int j = t; j < N; j += T) sm[j] = s[j ^ xin];
    }
  }
  __syncthreads();
  fft_rows_body<N, T>(sm, t, dir);
  for (int j = t; j < N; j += T) dline[j ^ xout] = sm[j];
}

// ---------------------------------------------------------------------------
// merged pyramid rows (inverse): one image per block (proven form).
// upMask: 1 = orientation mask on ups slots (s<3); 0 = plain pad (s3 expand2).
// ---------------------------------------------------------------------------
template<int N>
__global__ __launch_bounds__((N/4 < 64) ? 64 : N/4)
void ps_fft_rows_m(__half2* __restrict__ h4, __half2* __restrict__ bandD,
                   __half2* __restrict__ tiledD,
                   const __half2* __restrict__ lodS, const __half2* __restrict__ lodS1,
                   int nA, int h4First, int n, int srcH1, int upMask,
                   int moffB, float shiftB, int moffC, float shiftC, float scale)
{
  constexpr int T = (N/4 < 64) ? 64 : N/4;
  constexpr int XIN = N/2;
  __shared__ float2 sm[N];
  const int t = threadIdx.x;
  const int l = blockIdx.x & (N-1);
  const int img = blockIdx.x / N;

  if (img < nA){
    if (img == 0 && h4First){
      const __half2* s = h4 + (size_t)l*N;
      for (int j = t; j < N; j += T) sm[j] = h2f(s[j ^ XIN]);
    } else {
      const __half2* s = lodS + (size_t)l*N;
      for (int j = t; j < N; j += T) sm[j] = h2f(s[j ^ XIN]);
    }
  } else if (img < nA + 4){
    const int b = img - nA;
    const __half2* s = lodS + (size_t)l*N;
    for (int j = t; j < N; j += T){
      int x = j ^ XIN;
      float lr, ang; polar_f(moffB + l, moffB + x, lr, ang);
      float mf = f_hi(lr, shiftB) * band_am(ang, b);
      float2 v = h2f(s[x]);
      sm[j] = make_float2(-mf*v.y, mf*v.x);
    }
  } else {
    const int b = img - nA - 4;
    const int q = N/4;
    const int sl = l - q;
    if (sl < 0 || sl >= srcH1){
      __half2 z = f2h(make_float2(0.f, 0.f));
      if (tiledD){
        __half2* dl = tiledD + (size_t)img*n;
        for (int j = t; j < N; j += T)
          dl[(size_t)(j >> 3)*(size_t)(N*8) + ((size_t)l << 3) + (j & 7)] = z;
      } else {
        __half2* dl = h4 + (size_t)(img - 4)*n + (size_t)l*N;
        for (int j = t; j < N; j += T) dl[j] = z;
      }
      return;
    }
    const __half2* s = lodS1 + (size_t)sl*srcH1;
    for (int j = t; j < N; j += T){
      int p = j ^ XIN;
      float2 r = make_float2(0.f, 0.f);
      if (p >= q && p < q + srcH1){
        int x = p - q;
        float2 v = h2f(s[x]);
        if (upMask){
          float lr, ang; polar_f(moffC + sl, moffC + x, lr, ang);
          float mf = f_hi(lr, shiftC) * band_am(ang, b);
          r = make_float2(-mf*v.y, mf*v.x);
        } else {
          r = v;
        }
      }
      sm[j] = r;
    }
  }
  __syncthreads();
  fft_rows_body<N, T>(sm, t, +1.f);
  if (tiledD){
    __half2* dl = tiledD + (size_t)img*n;
    for (int j = t; j < N; j += T){
      float2 v = sm[j];
      dl[(size_t)(j >> 3)*(size_t)(N*8) + ((size_t)l << 3) + (j & 7)] =
        f2h(make_float2(v.x*scale, v.y*scale));
    }
  } else {
    __half2* dline;
    if (img < nA)          dline = h4 + (size_t)img*n + (size_t)l*N;
    else if (img < nA + 4) dline = bandD + (size_t)(img - nA)*n + (size_t)l*N;
    else                   dline = h4 + (size_t)(img - 4)*n + (size_t)l*N;
    for (int j = t; j < N; j += T){
      float2 v = sm[j];
      dline[j] = f2h(make_float2(v.x*scale, v.y*scale));
    }
  }
}

// ---------------------------------------------------------------------------
// simple FFT cols (f32 src, single image): SOP_HL / SOP_REAL(+stats)
// ---------------------------------------------------------------------------
template<int N, int CB>
__global__ __launch_bounds__(512)
void ps_fft_cols(const float2* __restrict__ src,
                 __half2* __restrict__ hdst, __half2* __restrict__ lodH,
                 float dir, int xin, int xout, float scale,
                 int sop, float* __restrict__ rdst, double* __restrict__ mout)
{
  constexpr int T = 512;
  constexpr int LCB = (CB==2)?1:(CB==4)?2:(CB==8)?3:4;
  constexpr int NE = N*CB;
  __shared__ float2 sm[NE];
  const int t = threadIdx.x;
  const int c0 = blockIdx.x * CB;
  const float2* sbase = src + c0;

  for (int e = t; e < NE; e += T){
    int j = e >> LCB, c = e & (CB - 1);
    sm[e] = sbase[(size_t)(j ^ xin)*N + c];
  }
  __syncthreads();
  fft_cols_body<N, CB, T>(sm, t, dir);

  if (sop == SOP_HL){
    for (int e = t; e < NE; e += T){
      int j = e >> LCB, c = e & (CB - 1);
      int row = j ^ xout, col = c0 + c;
      float lr, ang; polar_f(row, col, lr, ang);
      float lo = f_lo(lr, 0.f), hi = f_hi(lr, 0.f);
      float2 v = sm[j*CB + c];
      size_t o = (size_t)row*N + col;
      hdst[o] = f2h(make_float2(v.x*hi, v.y*hi));
      lodH[o] = f2h(make_float2(v.x*lo, v.y*lo));
    }
    return;
  }
  for (int e = t; e < NE; e += T){
    int j = e >> LCB, c = e & (CB - 1);
    rdst[(size_t)(j ^ xout)*N + c0 + c] = sm[j*CB + c].x * scale;
  }
  if (mout){
    float acc[5] = {0.f,0.f,0.f,0.f,0.f};
    for (int e = t; e < NE; e += T){
      float r = sm[e].x * scale, r2 = r*r;
      acc[0] += r; acc[1] += r2; acc[2] += r2*r; acc[3] += r2*r2; acc[4] += fabsf(r);
    }
    block_reduce_add_sc<5, 8>(acc, mout, (float*)sm);
  }
}

// ---------------------------------------------------------------------------
// merged pyramid cols (inverse; group A -> real+stats, others half2 out).
// srcT != null: 8-col-chunk tiled intermediate (full-granule reads).
// lpDst != null: ups slot writes real*4 -> lpDst (s3 expand2 fold).
// ---------------------------------------------------------------------------
template<int N, int CB>
__global__ __launch_bounds__(512)
void ps_fft_cols_m(__half2* __restrict__ h4, __half2* __restrict__ bandD,
                   const __half2* __restrict__ srcT,
                   int nA, int n,
                   float* __restrict__ rdst, int rimg, int rmask,
                   double* __restrict__ mout, int mstride,
                   float* __restrict__ lpDst)
{
  constexpr int T = 512;
  constexpr int LCB = (CB==2)?1:(CB==4)?2:(CB==8)?3:4;
  constexpr int NBK = N / CB;
  constexpr int NE = N*CB;
  constexpr int XIN = N/2;
  __shared__ float2 sm[NE];
  const int t = threadIdx.x;
  const int img = blockIdx.x / NBK;
  const int cg  = blockIdx.x % NBK;
  const int c0 = cg * CB;
  __half2* hbase;
  if (img < nA)          hbase = h4 + (size_t)img*n + c0;
  else if (img < nA + 4) hbase = bandD + (size_t)(img - nA)*n + c0;
  else                   hbase = h4 + (size_t)(img - 4)*n + c0;

  if (srcT){
    const __half2* sb = srcT + (size_t)img*n + (size_t)cg*(size_t)(CB*N);
    for (int e = t; e < NE; e += T){
      int j = e >> LCB, c = e & (CB - 1);
      sm[e] = h2f(sb[((j ^ XIN) << LCB) + c]);
    }
  } else {
    for (int e = t; e < NE; e += T){
      int j = e >> LCB, c = e & (CB - 1);
      sm[e] = h2f(hbase[(size_t)(j ^ XIN)*N + c]);
    }
  }
  __syncthreads();
  fft_cols_body<N, CB, T>(sm, t, +1.f);

  if (img < nA){
    if ((rmask >> img) & 1){
      for (int e = t; e < NE; e += T){
        int j = e >> LCB, c = e & (CB - 1);
        rdst[(size_t)img*(size_t)rimg + (size_t)j*N + c0 + c] = sm[j*CB + c].x;
      }
    }
    float acc[5] = {0.f,0.f,0.f,0.f,0.f};
    for (int e = t; e < NE; e += T){
      float r = sm[e].x, r2 = r*r;
      acc[0] += r; acc[1] += r2; acc[2] += r2*r; acc[3] += r2*r2; acc[4] += fabsf(r);
    }
    block_reduce_add_sc<5, 8>(acc, mout + (size_t)img*mstride, (float*)sm);
  } else if (img < nA + 4){
    for (int e = t; e < NE; e += T){
      int j = e >> LCB, c = e & (CB - 1);
      float2 v = sm[j*CB + c];
      hbase[(size_t)j*N + c] = f2h(v);
    }
  } else {
    if (lpDst){
      for (int e = t; e < NE; e += T){
        int j = e >> LCB, c = e & (CB - 1);
        lpDst[(size_t)j*N + c0 + c] = sm[j*CB + c].x * 4.f;   // expand2 x4
      }
    } else {
      for (int e = t; e < NE; e += T){
        int j = e >> LCB, c = e & (CB - 1);
        float2 v = sm[j*CB + c];
        hbase[(size_t)j*N + c] = f2h(make_float2(v.x*4.f, v.y*4.f));
      }
    }
  }
}

// ---------------------------------------------------------------------------
// spatial circular autocorrelation (proven round-8 1px form; bands half2).
// Family CLOSED: {1px,4px} x {nb=64,128,256} bracketed rounds 8-12, 20;
// nb=128 + 1px is the measured optimum (52us); nb=256 regressed to 70us
// (per-block fixed cost: 41-acc init + reduce + atomics dominates).
// ---------------------------------------------------------------------------
#define MAX_AC_TASKS 9
struct AcTaskTab {
  const void* src[MAX_AC_TASKS];
  int isMag[MAX_AC_TASKS];
  int H[MAX_AC_TASKS];
  int npi[MAX_AC_TASKS];
  int nb[MAX_AC_TASKS];
  int stOff[MAX_AC_TASKS];
  int stStride[MAX_AC_TASKS];
  int blkStart[MAX_AC_TASKS+1];
  int nTasks;
};

__global__ __launch_bounds__(256, 1)
void ps_spat_ac_multi(AcTaskTab tt, double* __restrict__ ST)
{
  __shared__ float tile[40*40];
  const int gb = blockIdx.x;
  int tk = 0;
  while (tk + 1 < tt.nTasks && gb >= tt.blkStart[tk+1]) tk++;
  const int lb  = gb - tt.blkStart[tk];
  const int nb  = tt.nb[tk];
  const int img = lb / nb;
  const int b0  = lb - img*nb;
  const int H = tt.H[tk];
  const int n_per_img = tt.npi[tk];
  const int isMag = tt.isMag[tk];
  const void* vsrc = tt.src[tk];
  const int t = threadIdx.x;
  const int tilesX = H >> 5;
  const int tiles = tilesX * tilesX;
  float acc[41];
  #pragma unroll
  for (int k = 0; k < 41; k++) acc[k] = 0.f;

  for (int tl = b0; tl < tiles; tl += nb){
    int by = tl / tilesX, bx = tl - by*tilesX;
    int y0 = by << 5, x0 = bx << 5;
    __syncthreads();
    for (int e = t; e < 40*40; e += 256){
      int ly = e / 40, lx = e - ly*40;
      int gy = (y0 + ly - 4) & (H - 1);
      int gx = (x0 + lx - 4) & (H - 1);
      float v;
      if (isMag){
        float2 c = h2f(((const __half2*)vsrc)[(size_t)img*n_per_img + (size_t)gy*H + gx]);
        v = sqrtf(c.x*c.x + c.y*c.y);
      } else {
        v = ((const float*)vsrc)[(size_t)img*n_per_img + (size_t)gy*H + gx];
      }
      tile[e] = v;
    }
    __syncthreads();
    for (int p = t; p < 32*32; p += 256){
      int py = p >> 5, px = p & 31;
      const float* row0 = tile + (py+4)*40 + (px+4);
      float c = row0[0];
      #pragma unroll
      for (int dx = 0; dx <= 4; dx++)
        acc[dx] += c * row0[dx];
      #pragma unroll
      for (int dy = 1; dy <= 4; dy++){
        const float* rw = row0 + dy*40;
        #pragma unroll
        for (int dx = -4; dx <= 4; dx++)
          acc[5 + (dy-1)*9 + (dx+4)] += c * rw[dx];
      }
    }
  }
  block_reduce_add<41, 4>(acc, ST + tt.stOff[tk] + (size_t)img*tt.stStride[tk]);
}

// ---------------------------------------------------------------------------
// crop chain: ALL levels 1..4 from lod[0] in ONE launch.
// ---------------------------------------------------------------------------
__global__ __launch_bounds__(256)
void ps_crop_all(__half2* __restrict__ l1, __half2* __restrict__ l2,
                 __half2* __restrict__ l3, __half2* __restrict__ l4,
                 const __half2* __restrict__ l0)
{
  int i = blockIdx.x*blockDim.x + threadIdx.x;
  int k, H;
  if (i < 262144){ k = 1; H = 512; }
  else if (i < 262144 + 65536){ k = 2; H = 256; i -= 262144; }
  else if (i < 262144 + 65536 + 16384){ k = 3; H = 128; i -= 262144 + 65536; }
  else if (i < 262144 + 65536 + 16384 + 4096){ k = 4; H = 64; i -= 262144 + 65536 + 16384; }
  else return;
  int y = i / H, x = i - y*H;
  const int offk = (k==1) ? 256 : (k==2) ? 384 : (k==3) ? 448 : 480;
  int oy = offk + y, ox = offk + x;
  float lr, ang; polar_f(oy, ox, lr, ang);
  float mk = f_lo(lr, -1.f);
  if (k >= 2) mk *= f_lo(lr, -2.f);
  if (k >= 3) mk *= f_lo(lr, -3.f);
  if (k >= 4) mk *= f_lo(lr, -4.f);
  float2 v = h2f(l0[(size_t)oy*1024 + ox]);
  __half2 r = f2h(make_float2(v.x*mk, v.y*mk));
  if (k == 1)      l1[(size_t)y*512 + x] = r;
  else if (k == 2) l2[(size_t)y*256 + x] = r;
  else if (k == 3) l3[(size_t)y*128 + x] = r;
  else             l4[(size_t)y*64  + x] = r;
}

// ---------------------------------------------------------------------------
// reductions
// ---------------------------------------------------------------------------
__global__ void ps_init_mm(unsigned* mm){ mm[0] = 0xFFFFFFFFu; mm[1] = 0u; }

__global__ __launch_bounds__(256, 1)
void ps_im_stats(const float4* __restrict__ x4, int n4, double* out, unsigned* mm){
  float acc[4] = {0.f,0.f,0.f,0.f};
  float mn = INFINITY, mx = -INFINITY;
  for (int i = blockIdx.x*blockDim.x + threadIdx.x; i < n4; i += gridDim.x*blockDim.x){
    float4 v = x4[i];
    float a0 = v.x, a1 = v.y, a2 = v.z, a3 = v.w;
    acc[0] += a0 + a1 + a2 + a3;
    acc[1] += a0*a0 + a1*a1 + a2*a2 + a3*a3;
    acc[2] += a0*a0*a0 + a1*a1*a1 + a2*a2*a2 + a3*a3*a3;
    acc[3] += a0*a0*a0*a0 + a1*a1*a1*a1 + a2*a2*a2*a2 + a3*a3*a3*a3;
    mn = fminf(mn, fminf(fminf(a0,a1), fminf(a2,a3)));
    mx = fmaxf(mx, fmaxf(fmaxf(a0,a1), fmaxf(a2,a3)));
  }
  block_reduce_add<4, 4>(acc, out);
  #pragma unroll
  for (int o = 32; o > 0; o >>= 1){
    mn = fminf(mn, __shfl_down(mn, o, 64));
    mx = fmaxf(mx, __shfl_down(mx, o, 64));
  }
  if ((threadIdx.x & 63) == 0){
    atomicMin(&mm[0], encf(mn));
    atomicMax(&mm[1], encf(mx));
  }
}

struct ScaleATab { const __half2* b[4]; int n[4]; };
__global__ __launch_bounds__(256, 1)
void ps_scaleA_multi(ScaleATab tt, double* __restrict__ ST){
  int s = blockIdx.y;
  int n = tt.n[s];
  if ((size_t)blockIdx.x*blockDim.x >= (size_t)n) return;
  const __half2* bb = tt.b[s];
  double* outp = ST + 64 + s*32;
  float acc[28];
  #pragma unroll
  for (int k = 0; k < 28; k++) acc[k] = 0.f;
  for (int i = blockIdx.x*blockDim.x + threadIdx.x; i < n; i += gridDim.x*blockDim.x){
    float2 v0 = h2f(bb[i]), v1 = h2f(bb[(size_t)n + i]),
           v2 = h2f(bb[2*(size_t)n + i]), v3 = h2f(bb[3*(size_t)n + i]);
    float ab[4] = { sqrtf(v0.x*v0.x+v0.y*v0.y), sqrtf(v1.x*v1.x+v1.y*v1.y),
                    sqrtf(v2.x*v2.x+v2.y*v2.y), sqrtf(v3.x*v3.x+v3.y*v3.y) };
    float re[4] = { v0.x, v1.x, v2.x, v3.x };
    #pragma unroll
    for (int a = 0; a < 4; a++){
      #pragma unroll
      for (int c = a; c < 4; c++){
        acc[P4(a,c)]      += ab[a]*ab[c];
        acc[10 + P4(a,c)] += re[a]*re[c];
      }
      acc[20 + a] += ab[a];
      acc[24 + a] += re[a];
    }
  }
  block_reduce_add<28, 4>(acc, outp);
}
__global__ __launch_bounds__(256, 1)
void ps_scaleB(const __half2* __restrict__ u0, const __half2* __restrict__ u1,
               const __half2* __restrict__ u2, const __half2* __restrict__ u3,
               const __half2* __restrict__ s0, const __half2* __restrict__ s1,
               const __half2* __restrict__ s2, const __half2* __restrict__ s3,
               int n, double* out){
  float acc[72];
  #pragma unroll
  for (int k = 0; k < 72; k++) acc[k] = 0.f;
  for (int i = blockIdx.x*blockDim.x + threadIdx.x; i < n; i += gridDim.x*blockDim.x){
    float2 u[4] = { h2f(u0[i]), h2f(u1[i]), h2f(u2[i]), h2f(u3[i]) };
    float2 bb[4] = { h2f(s0[i]), h2f(s1[i]), h2f(s2[i]), h2f(s3[i]) };
    float au[4], dre[4], dim[4], M[4], R[4];
    #pragma unroll
    for (int c = 0; c < 4; c++){
      float xx = u[c].x, yy = u[c].y;
      float mag = sqrtf(xx*xx + yy*yy);
      float den = mag + 1e-12f;
      au[c] = mag;
      dre[c] = (xx*xx - yy*yy)/den;
      dim[c] = (2.f*xx*yy)/den;
      M[c] = sqrtf(bb[c].x*bb[c].x + bb[c].y*bb[c].y);
      R[c] = bb[c].x;
    }
    #pragma unroll
    for (int c = 0; c < 4; c++){
      acc[c]      += au[c];
      acc[4 + c]  += au[c]*au[c];
      acc[24 + c] += dre[c];
      acc[28 + c] += dim[c];
      acc[32 + c] += dre[c]*dre[c];
      acc[36 + c] += dim[c]*dim[c];
    }
    #pragma unroll
    for (int a = 0; a < 4; a++)
      #pragma unroll
      for (int c = 0; c < 4; c++){
        acc[8 + a*4 + c]  += M[a]*au[c];
        acc[40 + a*4 + c] += R[a]*dre[c];
        acc[56 + a*4 + c] += R[a]*dim[c];
      }
  }
  block_reduce_add<72, 4>(acc, out);
}
__global__ __launch_bounds__(256, 1)
void ps_scaleC(const __half2* __restrict__ s0, const __half2* __restrict__ s1,
               const __half2* __restrict__ s2, const __half2* __restrict__ s3,
               const float* __restrict__ lp, int n, double* out){
  float acc[36];
  #pragma unroll
  for (int k = 0; k < 36; k++) acc[k] = 0.f;
  for (int i = blockIdx.x*blockDim.x + threadIdx.x; i < n; i += gridDim.x*blockDim.x){
    int y = i >> 7, x = i & 127;
    float L[5];
    L[0] = lp[i];
    L[1] = lp[(y << 7) | ((x + 126) & 127)];
    L[2] = lp[(y << 7) | ((x + 2) & 127)];
    L[3] = lp[(((y + 126) & 127) << 7) | x];
    L[4] = lp[(((y + 2) & 127) << 7) | x];
    float R[4] = { h2f(s0[i]).x, h2f(s1[i]).x, h2f(s2[i]).x, h2f(s3[i]).x };
    acc[0] += L[0];
    #pragma unroll
    for (int a = 0; a < 5; a++)
      #pragma unroll
      for (int c = a; c < 5; c++)
        acc[1 + P5(a,c)] += L[a]*L[c];
    #pragma unroll
    for (int a = 0; a < 4; a++)
      #pragma unroll
      for (int j = 0; j < 5; j++)
        acc[16 + a*5 + j] += R[a]*L[j];
  }
  block_reduce_add<36, 4>(acc, out);
}

// ---------------------------------------------------------------------------
// finalize — one thread per output element (layout unchanged)
// ---------------------------------------------------------------------------
__device__ __forceinline__ double d_ns(int s){ double h = (double)(1024 >> s); return h*h; }
__device__ __forceinline__ void d_moments(const double* Mo, double n,
                                          double& sk, double& ku, double& var){
  double m = Mo[0]/n, e2 = Mo[1]/n, e3 = Mo[2]/n, e4 = Mo[3]/n;
  var = e2 - m*m;
  double c3 = e3 - 3.0*m*e2 + 2.0*m*m*m;
  double c4 = e4 - 4.0*m*e3 + 6.0*m*m*e2 - 3.0*m*m*m*m;
  sk = c3/pow(var,1.5); ku = c4/(var*var);
}
__device__ __forceinline__ int ac_o(int w){
  int dy = w/9 - 4, dx = w - (w/9)*9 - 4;
  int ady = dy, adx = dx;
  if (dy < 0 || (dy == 0 && dx < 0)){ ady = -dy; adx = -dx; }
  return (ady == 0) ? adx : (5 + (ady-1)*9 + (adx+4));
}

__global__ __launch_bounds__(256)
void ps_finalize(const double* __restrict__ ST, const unsigned* __restrict__ MM,
                 float* __restrict__ out, int out_size){
  int idx = blockIdx.x*blockDim.x + threadIdx.x;
  if (idx >= out_size) return;
  const double n0 = 1048576.0;
  double val = 0.0;

  if (idx <= 5){
    if (idx == 4){ out[4] = decf(MM[0]); return; }
    if (idx == 5){ out[5] = decf(MM[1]); return; }
    double sk, ku, v; d_moments(ST, n0, sk, ku, v);
    val = (idx == 0) ? ST[0]/n0 : (idx == 1) ? v : (idx == 2) ? sk : ku;
  } else if (idx == 6){
    val = ST[8]/n0;
  } else if (idx <= 22){
    int i = idx - 7; int s = i >> 2, b = i & 3;
    val = ST[64 + s*32 + 20 + b] / d_ns(s);
  } else if (idx == 23){
    val = ST[10 + 4*6 + 4] / 4096.0;
  } else if (idx <= 1319){                      // band-mag ACs
    int i = idx - 24; int w = i >> 4; int j = i & 15;
    int s = j >> 2, b = j & 3;
    double n = d_ns(s);
    const double* R = ST + 752 + j*48;
    double mu = ST[64 + s*32 + 20 + b]/n, mu2 = mu*mu;
    int o = ac_o(w);
    val = (R[o]/n - mu2) / (R[0]/n - mu2 + 1e-12);
  } else if (idx <= 1329){                      // skew_r / kurt_r
    int i = idx - 1320; bool kq = (i >= 5); int r = kq ? i - 5 : i;
    double n = (r == 4) ? 4096.0 : d_ns(r);
    double sk, ku, v; d_moments(ST + 10 + r*6, n, sk, ku, v);
    val = kq ? ku : sk;
  } else if (idx <= 1734){                      // recon ACs
    int i = idx - 1330; int w = i / 5; int r = i - w*5;
    double n = (r == 4) ? 4096.0 : d_ns(r);
    const double* R = ST + 512 + r*48;
    double mu = ST[10 + r*6]/n, mu2 = mu*mu;
    int o = ac_o(w);
    val = (R[o]/n - mu2) / (R[0]/n - mu2 + 1e-12);
  } else if (idx <= 1739){                      // std_r
    int r = idx - 1735;
    double n = (r == 4) ? 4096.0 : d_ns(r);
    double sk, ku, v; d_moments(ST + 10 + r*6, n, sk, ku, v);
    val = sqrt(v);
  } else if (idx <= 1819){                      // com
    int i = idx - 1740; int s = i % 5; int q = i / 5; int a = q >> 2, b = q & 3;
    if (s < 4){
      double n = d_ns(s); const double* A = ST + 64 + s*32;
      double ma = A[20+a]/n, mb = A[20+b]/n;
      double caa = A[P4(a,a)]/n - ma*ma, cbb = A[P4(b,b)]/n - mb*mb;
      int lo = a < b ? a : b, hi = a < b ? b : a;
      double cab = A[P4(lo,hi)]/n - ma*mb;
      val = cab / (sqrt(caa)*sqrt(cbb) + 1e-12);
    }
  } else if (idx <= 1883){                      // csm
    int i = idx - 1820; int s = i & 3; int q = i >> 2; int a = q >> 2, c = q & 3;
    if (s < 3){
      double n = d_ns(s); const double* A = ST + 64 + s*32; const double* B = ST + 192 + s*80;
      double mM = A[20+a]/n; double sdM = sqrt(A[P4(a,a)]/n - mM*mM);
      double mU = B[c]/n;    double sdU = sqrt(B[4+c]/n - mU*mU);
      val = (B[8 + a*4 + c]/n - mM*mU) / (sdM*sdU + 1e-12);
    }
  } else if (idx <= 2203){                      // cor
    int i = idx - 1884; int s = i % 5; int q = i / 5; int a = q >> 3, b = q & 7;
    if (s < 4){
      if (a < 4 && b < 4){
        double n = d_ns(s); const double* A = ST + 64 + s*32;
        double ma = A[24+a]/n, mb = A[24+b]/n;
        double caa = A[10+P4(a,a)]/n - ma*ma, cbb = A[10+P4(b,b)]/n - mb*mb;
        int lo = a < b ? a : b, hi = a < b ? b : a;
        double cab = A[10+P4(lo,hi)]/n - ma*mb;
        val = cab / (sqrt(caa)*sqrt(cbb) + 1e-12);
      }
    } else {
      if (a < 5 && b < 5){
        const double* C = ST + 432; const double n3 = 16384.0;
        double lb = C[0]/n3;
        double caa = C[1+P5(a,a)]/n3 - lb*lb, cbb = C[1+P5(b,b)]/n3 - lb*lb;
        int lo = a < b ? a : b, hi = a < b ? b : a;
        double cab = C[1+P5(lo,hi)]/n3 - lb*lb;
        val = cab / (sqrt(caa)*sqrt(cbb) + 1e-12);
      }
    }
  } else if (idx <= 2459){                      // csr
    int i = idx - 2204; int s = i & 3; int q = i >> 2; int a = q >> 3, c = q & 7;
    if (a < 4){
      double n = d_ns(s); const double* A = ST + 64 + s*32;
      double mR = A[24+a]/n; double sdR = sqrt(A[10+P4(a,a)]/n - mR*mR);
      if (s < 3 && c < 8){
        const double* B = ST + 192 + s*80;
        if (c < 4){
          double md = B[24+c]/n; double sd = sqrt(B[32+c]/n - md*md);
          val = (B[40 + a*4 + c]/n - mR*md) / (sdR*sd + 1e-12);
        } else {
          int cc = c - 4;
          double md = B[28+cc]/n; double sd = sqrt(B[36+cc]/n - md*md);
          val = (B[56 + a*4 + cc]/n - mR*md) / (sdR*sd + 1e-12);
        }
      } else if (s == 3 && c < 5){
        const double* C = ST + 432; const double n3 = 16384.0;
        double lb = C[0]/n3;
        double sdL = sqrt(C[1+P5(c,c)]/n3 - lb*lb);
        val = (C[16 + a*5 + c]/n3 - mR*lb) / (sdR*sdL + 1e-12);
      }
    }
  } else {
    val = ST[5]/n0 - (ST[4]/n0)*(ST[4]/n0);
  }
  out[idx] = (float)val;
}

// ---------------------------------------------------------------------------
// host orchestration
// ---------------------------------------------------------------------------
static void rows_s(int H, float2* dst, const void* src, int srcH1,
                   float dir, int xin, int xout, int lop, int srcHalf, hipStream_t st){
  dim3 g(H);
  switch (H){
    case 64:   ps_fft_rows<64>  <<<g, 64,  0, st>>>(dst, src, srcH1, dir, xin, xout, lop, srcHalf); break;
    case 128:  ps_fft_rows<128> <<<g, 64,  0, st>>>(dst, src, srcH1, dir, xin, xout, lop, srcHalf); break;
    case 256:  ps_fft_rows<256> <<<g, 64,  0, st>>>(dst, src, srcH1, dir, xin, xout, lop, srcHalf); break;
    case 512:  ps_fft_rows<512> <<<g, 128, 0, st>>>(dst, src, srcH1, dir, xin, xout, lop, srcHalf); break;
    case 1024: ps_fft_rows<1024><<<g, 256, 0, st>>>(dst, src, srcH1, dir, xin, xout, lop, srcHalf); break;
    default: break;
  }
}
static void cols_s(int H, const float2* src, __half2* hdst, __half2* lodH,
                   float dir, int xin, int xout, float scale,
                   int sop, float* rdst, double* mout, hipStream_t st){
  switch (H){
    case 64:   ps_fft_cols<64,16>  <<<dim3(64/16),  512, 0, st>>>(src, hdst, lodH, dir, xin, xout, scale, sop, rdst, mout); break;
    case 128:  ps_fft_cols<128,16> <<<dim3(128/16), 512, 0, st>>>(src, hdst, lodH, dir, xin, xout, scale, sop, rdst, mout); break;
    case 256:  ps_fft_cols<256,16> <<<dim3(256/16), 512, 0, st>>>(src, hdst, lodH, dir, xin, xout, scale, sop, rdst, mout); break;
    case 512:  ps_fft_cols<512,16> <<<dim3(512/16), 512, 0, st>>>(src, hdst, lodH, dir, xin, xout, scale, sop, rdst, mout); break;
    case 1024: ps_fft_cols<1024,8> <<<dim3(1024/8), 512, 0, st>>>(src, hdst, lodH, dir, xin, xout, scale, sop, rdst, mout); break;
    default: break;
  }
}
static void rows_m(int H, __half2* h4, __half2* bandD, __half2* tiledD,
                   const __half2* lodS, const __half2* lodS1,
                   int nA, int h4First, int nimg, int n, int srcH1, int upMask,
                   int moffB, float shiftB, int moffC, float shiftC, float scale, hipStream_t st){
  dim3 g(nimg * H);
  switch (H){
    case 128:  ps_fft_rows_m<128> <<<g, 64,  0, st>>>(h4, bandD, tiledD, lodS, lodS1, nA, h4First, n, srcH1, upMask, moffB, shiftB, moffC, shiftC, scale); break;
    case 256:  ps_fft_rows_m<256> <<<g, 64,  0, st>>>(h4, bandD, tiledD, lodS, lodS1, nA, h4First, n, srcH1, upMask, moffB, shiftB, moffC, shiftC, scale); break;
    case 512:  ps_fft_rows_m<512> <<<g, 128, 0, st>>>(h4, bandD, tiledD, lodS, lodS1, nA, h4First, n, srcH1, upMask, moffB, shiftB, moffC, shiftC, scale); break;
    case 1024: ps_fft_rows_m<1024><<<g, 256, 0, st>>>(h4, bandD, tiledD, lodS, lodS1, nA, h4First, n, srcH1, upMask, moffB, shiftB, moffC, shiftC, scale); break;
    default: break;
  }
}
static void cols_m(int H, __half2* h4, __half2* bandD, const __half2* srcT,
                   int nA, int nimg, int n,
                   float* rdst, int rimg, int rmask, double* mout, int mstride,
                   float* lpDst, hipStream_t st){
  switch (H){
    case 128:  ps_fft_cols_m<128,16> <<<dim3(nimg*(128/16)), 512, 0, st>>>(h4, bandD, srcT, nA, n, rdst, rimg, rmask, mout, mstride, lpDst); break;
    case 256:  ps_fft_cols_m<256,16> <<<dim3(nimg*(256/16)), 512, 0, st>>>(h4, bandD, srcT, nA, n, rdst, rimg, rmask, mout, mstride, lpDst); break;
    case 512:  ps_fft_cols_m<512,16> <<<dim3(nimg*(512/16)), 512, 0, st>>>(h4, bandD, srcT, nA, n, rdst, rimg, rmask, mout, mstride, lpDst); break;
    case 1024: ps_fft_cols_m<1024,8> <<<dim3(nimg*(1024/8)), 512, 0, st>>>(h4, bandD, srcT, nA, n, rdst, rimg, rmask, mout, mstride, lpDst); break;
    default: break;
  }
}

static inline dim3 gr(int n){ return dim3((n + 255)/256); }
static inline int  rblocks(int n){ int b = (n + 255)/256; return b > 512 ? 512 : b; }

#define FWD (-1.0f)
#define INV (+1.0f)

extern "C" void kernel_launch(void* const* d_in, const int* in_sizes, int n_in,
                              void* d_out, int out_size, void* d_ws, size_t ws_size,
                              hipStream_t stream){
  (void)in_sizes; (void)n_in;
  const float* im = (const float*)d_in[0];
  float* out = (float*)d_out;

  const int Hs[5]   = {1024, 512, 256, 128, 64};
  const int offs[5] = {0, 256, 384, 448, 480};

  // ---- carve workspace ----
  char* base = (char*)d_ws;
  size_t off = 0;
  auto carve = [&](size_t bytes)->void*{
    void* r = base + off;
    off = (off + bytes + 255) & ~(size_t)255;
    return r;
  };
  const int n0 = 1024*1024;
  __half2* lod[5];
  for (int s = 0; s < 5; s++) lod[s] = (__half2*)carve((size_t)Hs[s]*Hs[s]*sizeof(__half2));
  __half2* band[4];
  for (int s = 0; s < 4; s++) band[s] = (__half2*)carve((size_t)4*Hs[s]*Hs[s]*sizeof(__half2));
  float* reals0 = (float*)carve((size_t)2*n0*sizeof(float));
  float* recon[5];
  recon[0] = reals0 + n0;
  for (int s = 1; s < 5; s++) recon[s] = (float*)carve((size_t)Hs[s]*Hs[s]*sizeof(float));
  float* lp = (float*)carve(128*128*sizeof(float));
  float2* scrF = (float2*)carve((size_t)n0*sizeof(float2));
  __half2* h4 = (__half2*)carve((size_t)6*n0*sizeof(__half2));
  __half2* hInt = (__half2*)carve((size_t)10*n0*sizeof(__half2));  // s0 tiled intermediate
  double* ST = (double*)carve(2048*sizeof(double));
  unsigned* MM = (unsigned*)carve(64*sizeof(unsigned));
  if (off > ws_size) return;

  // ---- init ----
  hipMemsetAsync(ST, 0, 2048*sizeof(double), stream);
  ps_init_mm<<<1, 1, 0, stream>>>(MM);
  ps_im_stats<<<256, 256, 0, stream>>>((const float4*)im, n0/4, ST + 0, MM);

  // ---- imdft (shifted); cols fuses radial masks:
  //      h4[0] = hi*V (half), lod[0] = lo*V (half) ----
  rows_s(1024, scrF, im, 0, FWD, 0, 512, LOP_R2C, 0, stream);
  cols_s(1024, scrF, h4, lod[0], FWD, 0, 512, 1.0f, SOP_HL, nullptr, nullptr, stream);

  // ---- whole crop chain in one launch ----
  ps_crop_all<<<gr(262144 + 65536 + 16384 + 4096), 256, 0, stream>>>(
      lod[1], lod[2], lod[3], lod[4], lod[0]);

  // ---- pyramid scales: merged rows+cols pair per scale
  //      (s3 additionally carries the lowpass expand2 as an unmasked up) ----
  for (int s = 0; s < 4; s++){
    int H = Hs[s], n = H*H;
    float invn = 1.0f/((float)H*(float)H);
    int nA = (s == 0) ? 2 : 1;
    int nups = (s < 3) ? 4 : 1;
    int nimg = nA + 4 + nups;
    int upMask = (s < 3) ? 1 : 0;
    __half2* tD = (s == 0) ? hInt : nullptr;
    rows_m(H, h4, band[s], tD, lod[s], lod[s+1], nA, (s == 0) ? 1 : 0, nimg, n, Hs[s+1],
           upMask, offs[s], -(float)(s+1), offs[s+1], -(float)(s+2), invn, stream);
    float* rT = (s == 0) ? reals0 : recon[s];
    int rimg = (s == 0) ? n0 : 0;
    int rmask = (s == 0) ? 2 : 1;
    double* mT = (s == 0) ? (ST + 4) : (ST + 10 + s*6);
    int mstr = (s == 0) ? 6 : 0;
    float* lpD = (s == 3) ? lp : nullptr;
    cols_m(H, h4, band[s], tD, nA, nimg, n, rT, rimg, rmask, mT, mstr, lpD, stream);
    if (s < 3){
      __half2* u = h4 + (size_t)nA*n;
      ps_scaleB<<<rblocks(n), 256, 0, stream>>>(u, u+n, u+2*(size_t)n, u+3*(size_t)n,
                                                band[s], band[s]+n, band[s]+2*(size_t)n, band[s]+3*(size_t)n,
                                                n, ST + 192 + s*80);
    }
  }
  // lowpass recon (lod[4] half -> f32 fft)
  rows_s(64, scrF, lod[4], 0, INV, 32, 0, LOP_NONE, 1, stream);
  cols_s(64, scrF, nullptr, nullptr, INV, 32, 0, 1.0f/4096.f, SOP_REAL, recon[4], ST + 34, stream);
  ps_scaleC<<<rblocks(16384), 256, 0, stream>>>(band[3], band[3]+16384, band[3]+2*16384, band[3]+3*16384,
                                                lp, 16384, ST + 432);

  // ---- all 21 autocorrelations in one launch (big tasks first, nb<=128) ----
  {
    AcTaskTab tt{};
    int nt = 0, blk = 0;
    auto addTask = [&](const void* src, int isMag, int H, int nimgs, int stOff){
      int tiles = (H>>5)*(H>>5);
      int nb = tiles < 128 ? tiles : 128;
      tt.src[nt] = src; tt.isMag[nt] = isMag; tt.H[nt] = H; tt.npi[nt] = H*H;
      tt.nb[nt] = nb; tt.stOff[nt] = stOff; tt.stStride[nt] = 48;
      tt.blkStart[nt] = blk; blk += nb*nimgs; nt++;
    };
    addTask(band[0], 1, 1024, 4, 752 + 0*4*48);
    addTask(recon[0], 0, 1024, 1, 512 + 0*48);
    addTask(band[1], 1, 512, 4, 752 + 1*4*48);
    addTask(recon[1], 0, 512, 1, 512 + 1*48);
    addTask(band[2], 1, 256, 4, 752 + 2*4*48);
    addTask(recon[2], 0, 256, 1, 512 + 2*48);
    addTask(band[3], 1, 128, 4, 752 + 3*4*48);
    addTask(recon[3], 0, 128, 1, 512 + 3*48);
    addTask(recon[4], 0, 64, 1, 512 + 4*48);
    tt.blkStart[nt] = blk; tt.nTasks = nt;
    ps_spat_ac_multi<<<dim3(blk), 256, 0, stream>>>(tt, ST);
  }

  // ---- per-scale band Grams (one launch) ----
  {
    ScaleATab ta{};
    for (int s = 0; s < 4; s++){ ta.b[s] = band[s]; ta.n[s] = Hs[s]*Hs[s]; }
    ps_scaleA_multi<<<dim3(512, 4), 256, 0, stream>>>(ta, ST);
  }

  // ---- finalize ----
  ps_finalize<<<gr(out_size), 256, 0, stream>>>(ST, MM, out, out_size);
}